// Round 1
// baseline (1334.858 us; speedup 1.0000x reference)
//
#include <hip/hip_runtime.h>
#include <math.h>

#define N_NODES 50000
#define E_EDGES 800000
#define ET (E_EDGES + N_NODES)   // edges + self loops
#define L_LAYERS 4

__device__ __forceinline__ float gelu_f(float x) {
    // exact gelu: 0.5*x*(1+erf(x/sqrt(2)))
    return 0.5f * x * (1.0f + erff(x * 0.70710678118654752f));
}

// ---------------- graph preprocessing ----------------

__global__ __launch_bounds__(256) void count_deg(const int* __restrict__ ecol,
                                                 int* __restrict__ cnt) {
    int e = blockIdx.x * 256 + threadIdx.x;
    if (e >= ET) return;
    int c = (e < E_EDGES) ? ecol[e] : (e - E_EDGES);
    atomicAdd(&cnt[c], 1);
}

__global__ __launch_bounds__(1024) void scan_deg(const int* __restrict__ cnt,
                                                 int* __restrict__ ptrb,
                                                 float* __restrict__ dinv) {
    __shared__ int sums[1024];
    int tid = threadIdx.x;
    const int CH = (N_NODES + 1023) / 1024;  // 49
    int base = tid * CH;
    int s = 0;
    for (int j = 0; j < CH; ++j) {
        int idx = base + j;
        if (idx < N_NODES) {
            int c = cnt[idx];
            s += c;
            dinv[idx] = rsqrtf((float)c);   // deg >= 1 (self loop)
        }
    }
    sums[tid] = s;
    __syncthreads();
    for (int off = 1; off < 1024; off <<= 1) {
        int v = (tid >= off) ? sums[tid - off] : 0;
        __syncthreads();
        sums[tid] += v;
        __syncthreads();
    }
    int prefix = sums[tid] - s;  // exclusive prefix at chunk start
    for (int j = 0; j < CH; ++j) {
        int idx = base + j;
        if (idx < N_NODES) {
            ptrb[idx] = prefix;
            prefix += cnt[idx];
        }
    }
    if (tid == 1023) ptrb[N_NODES] = sums[1023];
}

__global__ __launch_bounds__(256) void bucket(const int* __restrict__ erow,
                                              const int* __restrict__ ecol,
                                              const int* __restrict__ ptrb,
                                              int* __restrict__ fill,
                                              const float* __restrict__ dinv,
                                              int* __restrict__ esrc,
                                              float* __restrict__ enorm) {
    int e = blockIdx.x * 256 + threadIdx.x;
    if (e >= ET) return;
    int r, c;
    if (e < E_EDGES) { r = erow[e]; c = ecol[e]; }
    else             { r = e - E_EDGES; c = r; }
    int pos = ptrb[c] + atomicAdd(&fill[c], 1);
    esrc[pos]  = r;
    enorm[pos] = dinv[r] * dinv[c];
}

// ---------------- GEMMs (f32, vector ALU; no fp32 MFMA on CDNA4) ----------------

// C[N,128] = A[N,128] @ W[128,128].  128 rows/block, K in 2 chunks of 64.
// LDS: At k-major (so fragment reads are b128 + broadcast), W row-major.
__global__ __launch_bounds__(256, 2) void gemm128(const float* __restrict__ A,
                                                  const float* __restrict__ W,
                                                  float* __restrict__ C) {
    __shared__ float At[64 * 128];   // [kk][r]
    __shared__ float Wl[64 * 128];   // [kk][c]
    int tid  = threadIdx.x;
    int row0 = blockIdx.x * 128;
    int tx = tid & 15;               // c0 = tx*8
    int ty = tid >> 4;               // r0 = ty*8
    float acc[8][8];
#pragma unroll
    for (int i = 0; i < 8; ++i)
#pragma unroll
        for (int j = 0; j < 8; ++j) acc[i][j] = 0.f;

    const int r_ld  = tid >> 1;
    const int kb_ld = (tid & 1) * 32;
    const int wk_ld = tid >> 2;
    const int wc_ld = (tid & 3) * 32;

    for (int kc = 0; kc < 2; ++kc) {
        int gr = row0 + r_ld;
#pragma unroll
        for (int i = 0; i < 8; ++i) {
            int kl = kb_ld + i * 4;
            float4 v = make_float4(0.f, 0.f, 0.f, 0.f);
            if (gr < N_NODES)
                v = *(const float4*)(A + (size_t)gr * 128 + kc * 64 + kl);
            At[(kl + 0) * 128 + r_ld] = v.x;
            At[(kl + 1) * 128 + r_ld] = v.y;
            At[(kl + 2) * 128 + r_ld] = v.z;
            At[(kl + 3) * 128 + r_ld] = v.w;
        }
#pragma unroll
        for (int i = 0; i < 8; ++i) {
            *(float4*)(Wl + wk_ld * 128 + wc_ld + 4 * i) =
                *(const float4*)(W + (size_t)(kc * 64 + wk_ld) * 128 + wc_ld + 4 * i);
        }
        __syncthreads();
#pragma unroll 2
        for (int kk = 0; kk < 64; ++kk) {
            float4 a0 = *(float4*)(At + kk * 128 + ty * 8);
            float4 a1 = *(float4*)(At + kk * 128 + ty * 8 + 4);
            float4 w0 = *(float4*)(Wl + kk * 128 + tx * 8);
            float4 w1 = *(float4*)(Wl + kk * 128 + tx * 8 + 4);
            float av[8] = {a0.x, a0.y, a0.z, a0.w, a1.x, a1.y, a1.z, a1.w};
            float wv[8] = {w0.x, w0.y, w0.z, w0.w, w1.x, w1.y, w1.z, w1.w};
#pragma unroll
            for (int i = 0; i < 8; ++i)
#pragma unroll
                for (int j = 0; j < 8; ++j) acc[i][j] += av[i] * wv[j];
        }
        __syncthreads();
    }
#pragma unroll
    for (int i = 0; i < 8; ++i) {
        int gr = row0 + ty * 8 + i;
        if (gr < N_NODES) {
            float4 o0 = make_float4(acc[i][0], acc[i][1], acc[i][2], acc[i][3]);
            float4 o1 = make_float4(acc[i][4], acc[i][5], acc[i][6], acc[i][7]);
            *(float4*)(C + (size_t)gr * 128 + tx * 8)     = o0;
            *(float4*)(C + (size_t)gr * 128 + tx * 8 + 4) = o1;
        }
    }
}

// C[N,64] = A[N,64] @ W[64,64] + b[64].  128 rows/block, single K chunk.
__global__ __launch_bounds__(256, 3) void gemm64(const float* __restrict__ A,
                                                 const float* __restrict__ W,
                                                 const float* __restrict__ b,
                                                 float* __restrict__ C) {
    __shared__ float At[64 * 128];   // [k][r]  32KB
    __shared__ float Wl[64 * 64];    // [k][c]  16KB
    int tid  = threadIdx.x;
    int row0 = blockIdx.x * 128;
    int tx = tid & 7;                // c0 = tx*8
    int ty = tid >> 3;               // r0 = ty*4 (ty 0..31)
    float acc[4][8];
#pragma unroll
    for (int i = 0; i < 4; ++i)
#pragma unroll
        for (int j = 0; j < 8; ++j) acc[i][j] = 0.f;

    {
        int r_ld  = tid >> 1;
        int kb_ld = (tid & 1) * 32;
        int gr = row0 + r_ld;
#pragma unroll
        for (int i = 0; i < 8; ++i) {
            int kl = kb_ld + i * 4;
            float4 v = make_float4(0.f, 0.f, 0.f, 0.f);
            if (gr < N_NODES) v = *(const float4*)(A + (size_t)gr * 64 + kl);
            At[(kl + 0) * 128 + r_ld] = v.x;
            At[(kl + 1) * 128 + r_ld] = v.y;
            At[(kl + 2) * 128 + r_ld] = v.z;
            At[(kl + 3) * 128 + r_ld] = v.w;
        }
        int wk = tid >> 2;
        int wc = (tid & 3) * 16;
#pragma unroll
        for (int i = 0; i < 4; ++i)
            *(float4*)(Wl + wk * 64 + wc + 4 * i) =
                *(const float4*)(W + (size_t)wk * 64 + wc + 4 * i);
    }
    __syncthreads();
#pragma unroll 2
    for (int k = 0; k < 64; ++k) {
        float4 a0 = *(float4*)(At + k * 128 + ty * 4);
        float4 w0 = *(float4*)(Wl + k * 64 + tx * 8);
        float4 w1 = *(float4*)(Wl + k * 64 + tx * 8 + 4);
        float av[4] = {a0.x, a0.y, a0.z, a0.w};
        float wv[8] = {w0.x, w0.y, w0.z, w0.w, w1.x, w1.y, w1.z, w1.w};
#pragma unroll
        for (int i = 0; i < 4; ++i)
#pragma unroll
            for (int j = 0; j < 8; ++j) acc[i][j] += av[i] * wv[j];
    }
    float bj[8];
#pragma unroll
    for (int j = 0; j < 8; ++j) bj[j] = b[tx * 8 + j];
#pragma unroll
    for (int i = 0; i < 4; ++i) {
        int gr = row0 + ty * 4 + i;
        if (gr < N_NODES) {
            float4 o0 = make_float4(acc[i][0] + bj[0], acc[i][1] + bj[1],
                                    acc[i][2] + bj[2], acc[i][3] + bj[3]);
            float4 o1 = make_float4(acc[i][4] + bj[4], acc[i][5] + bj[5],
                                    acc[i][6] + bj[6], acc[i][7] + bj[7]);
            *(float4*)(C + (size_t)gr * 64 + tx * 8)     = o0;
            *(float4*)(C + (size_t)gr * 64 + tx * 8 + 4) = o1;
        }
    }
}

// ---------------- edge aggregation (one wave per dst) ----------------

__global__ __launch_bounds__(256) void agg128(const float* __restrict__ h2,
                                              const int* __restrict__ ptrb,
                                              const int* __restrict__ esrc,
                                              const float* __restrict__ enorm,
                                              const float* __restrict__ bias,
                                              float* __restrict__ out,
                                              int apply_gelu) {
    int dst  = (blockIdx.x * 256 + threadIdx.x) >> 6;
    int lane = threadIdx.x & 63;
    if (dst >= N_NODES) return;
    int p0 = ptrb[dst], p1 = ptrb[dst + 1];
    float acc0 = 0.f, acc1 = 0.f;
    for (int p = p0; p < p1; ++p) {
        int src  = esrc[p];
        float nv = enorm[p];
        const float* hr = h2 + (size_t)src * 128;
        acc0 += nv * hr[lane];
        acc1 += nv * hr[lane + 64];
    }
    float v0 = acc0 + bias[lane];
    float v1 = acc1 + bias[lane + 64];
    if (apply_gelu) { v0 = gelu_f(v0); v1 = gelu_f(v1); }
    out[(size_t)dst * 128 + lane]      = v0;
    out[(size_t)dst * 128 + 64 + lane] = v1;
}

__global__ __launch_bounds__(256) void ta_kernel(const float* __restrict__ t,
                                                 const float* __restrict__ a,
                                                 float* __restrict__ ta) {
    int wid  = (blockIdx.x * 256 + threadIdx.x) >> 6;
    int lane = threadIdx.x & 63;
    if (wid >= N_NODES) return;
    float v = t[(size_t)wid * 64 + lane] * a[lane];
#pragma unroll
    for (int off = 32; off; off >>= 1) v += __shfl_xor(v, off);
    if (lane == 0) ta[wid] = v;
}

__global__ __launch_bounds__(256) void gna_agg(const float* __restrict__ t,
                                               const float* __restrict__ ta,
                                               const int* __restrict__ ptrb,
                                               const int* __restrict__ esrc,
                                               const float* __restrict__ base,
                                               float* __restrict__ gout) {
    int dst  = (blockIdx.x * 256 + threadIdx.x) >> 6;
    int lane = threadIdx.x & 63;
    if (dst >= N_NODES) return;
    int p0 = ptrb[dst], p1 = ptrb[dst + 1];
    float tac = ta[dst];
    // pass 1: segment max of alpha = tac - ta[src]
    float m = -1e30f;
    for (int p = p0 + lane; p < p1; p += 64) m = fmaxf(m, tac - ta[esrc[p]]);
#pragma unroll
    for (int off = 32; off; off >>= 1) m = fmaxf(m, __shfl_xor(m, off));
    // pass 2: denom
    float ssum = 0.f;
    for (int p = p0 + lane; p < p1; p += 64) ssum += expf(tac - ta[esrc[p]] - m);
#pragma unroll
    for (int off = 32; off; off >>= 1) ssum += __shfl_xor(ssum, off);
    float winv = 1.0f / (ssum + 1e-16f);
    // pass 3: weighted message, lane = feature dim
    float msg = 0.f;
    for (int p = p0; p < p1; ++p) {
        int src = esrc[p];
        float w = expf(tac - ta[src] - m) * winv;
        msg += w * t[(size_t)src * 64 + lane];
    }
    float v = base[(size_t)dst * 64 + lane] + msg;
    gout[(size_t)dst * 64 + lane] = gelu_f(v);
}

// ---------------- launch ----------------

extern "C" void kernel_launch(void* const* d_in, const int* in_sizes, int n_in,
                              void* d_out, int out_size, void* d_ws, size_t ws_size,
                              hipStream_t stream) {
    const float* x     = (const float*)d_in[0];
    const float* s     = (const float*)d_in[1];
    const int*   ei    = (const int*)d_in[2];
    const float* gcn_W = (const float*)d_in[3];
    const float* gcn_b = (const float*)d_in[4];
    const float* w1W   = (const float*)d_in[5];
    const float* w1b   = (const float*)d_in[6];
    const float* w2W   = (const float*)d_in[7];
    const float* w2b   = (const float*)d_in[8];
    const float* ga    = (const float*)d_in[9];

    float* h_out = (float*)d_out;                               // N x 128
    float* g_out = (float*)d_out + (size_t)N_NODES * 128;       // N x 64

    size_t off = 0;
    char* wsb = (char*)d_ws;
    auto take = [&](size_t bytes) {
        void* p = wsb + off;
        off = (off + bytes + 255) & ~(size_t)255;
        return p;
    };
    int*   cnt     = (int*)take((size_t)N_NODES * 4);
    int*   ptrb    = (int*)take((size_t)(N_NODES + 1) * 4);
    int*   fill    = (int*)take((size_t)N_NODES * 4);
    int*   esrc    = (int*)take((size_t)ET * 4);
    float* dinv    = (float*)take((size_t)N_NODES * 4);
    float* enorm   = (float*)take((size_t)ET * 4);
    float* h2      = (float*)take((size_t)N_NODES * 128 * 4);
    float* tbuf    = (float*)take((size_t)N_NODES * 64 * 4);
    float* basebuf = (float*)take((size_t)N_NODES * 64 * 4);
    float* tabuf   = (float*)take((size_t)N_NODES * 4);
    (void)ws_size; (void)in_sizes; (void)n_in; (void)out_size;

    const int* erow = ei;
    const int* ecol = ei + E_EDGES;

    hipMemsetAsync(cnt, 0, (size_t)N_NODES * 4, stream);
    hipMemsetAsync(fill, 0, (size_t)N_NODES * 4, stream);

    int ge = (ET + 255) / 256;
    count_deg<<<ge, 256, 0, stream>>>(ecol, cnt);
    scan_deg<<<1, 1024, 0, stream>>>(cnt, ptrb, dinv);
    bucket<<<ge, 256, 0, stream>>>(erow, ecol, ptrb, fill, dinv, esrc, enorm);

    const int gemm_blocks = (N_NODES + 127) / 128;   // 391
    const int wave_blocks = (N_NODES * 64 + 255) / 256;  // 12500

    // ---- GCN ----
    const float* hin = x;
    for (int l = 0; l < L_LAYERS; ++l) {
        gemm128<<<gemm_blocks, 256, 0, stream>>>(hin, gcn_W + (size_t)l * 128 * 128, h2);
        agg128<<<wave_blocks, 256, 0, stream>>>(h2, ptrb, esrc, enorm,
                                                gcn_b + (size_t)l * 128, h_out,
                                                (l < L_LAYERS - 1) ? 1 : 0);
        hin = h_out;
    }

    // ---- GNA ----
    const float* gin = s;
    for (int l = 0; l < L_LAYERS; ++l) {
        gemm64<<<gemm_blocks, 256, 0, stream>>>(gin, w2W + (size_t)l * 64 * 64,
                                                w2b + (size_t)l * 64, tbuf);
        gemm64<<<gemm_blocks, 256, 0, stream>>>(gin, w1W + (size_t)l * 64 * 64,
                                                w1b + (size_t)l * 64, basebuf);
        ta_kernel<<<wave_blocks, 256, 0, stream>>>(tbuf, ga + (size_t)l * 64, tabuf);
        gna_agg<<<wave_blocks, 256, 0, stream>>>(tbuf, tabuf, ptrb, esrc, basebuf, g_out);
        gin = g_out;
    }
}

// Round 2
// 857.551 us; speedup vs baseline: 1.5566x; 1.5566x over previous
//
#include <hip/hip_runtime.h>
#include <math.h>

#define N_NODES 50000
#define E_EDGES 800000
#define ET (E_EDGES + N_NODES)   // edges + self loops
#define L_LAYERS 4
#define NB_SCAN ((N_NODES + 255) / 256)   // 196

__device__ __forceinline__ float gelu_f(float x) {
    return 0.5f * x * (1.0f + erff(x * 0.70710678118654752f));
}

// ---------------- graph preprocessing ----------------

__global__ __launch_bounds__(256) void count_deg(const int* __restrict__ ecol,
                                                 int* __restrict__ cnt) {
    int e = blockIdx.x * 256 + threadIdx.x;
    if (e >= ET) return;
    int c = (e < E_EDGES) ? ecol[e] : (e - E_EDGES);
    atomicAdd(&cnt[c], 1);
}

// phase 1: per-block reduce of cnt
__global__ __launch_bounds__(256) void scan_part1(const int* __restrict__ cnt,
                                                  int* __restrict__ bsum) {
    __shared__ int red[256];
    int t = threadIdx.x;
    int i = blockIdx.x * 256 + t;
    red[t] = (i < N_NODES) ? cnt[i] : 0;
    __syncthreads();
#pragma unroll
    for (int off = 128; off; off >>= 1) {
        if (t < off) red[t] += red[t + off];
        __syncthreads();
    }
    if (t == 0) bsum[blockIdx.x] = red[0];
}

// phase 2: exclusive scan of the 196 block sums (single tiny block)
__global__ __launch_bounds__(256) void scan_part2(int* __restrict__ bsum) {
    __shared__ int sh[256];
    int t = threadIdx.x;
    int v = (t < NB_SCAN) ? bsum[t] : 0;
    sh[t] = v;
    __syncthreads();
    for (int off = 1; off < 256; off <<= 1) {
        int u = (t >= off) ? sh[t - off] : 0;
        __syncthreads();
        sh[t] += u;
        __syncthreads();
    }
    if (t < NB_SCAN) bsum[t] = sh[t] - v;   // exclusive
}

// phase 3: per-block exclusive rescan + offset; also emits dinv
__global__ __launch_bounds__(256) void scan_part3(const int* __restrict__ cnt,
                                                  const int* __restrict__ bsum,
                                                  int* __restrict__ ptrb,
                                                  float* __restrict__ dinv) {
    __shared__ int sh[256];
    int t = threadIdx.x;
    int i = blockIdx.x * 256 + t;
    int v = (i < N_NODES) ? cnt[i] : 0;
    sh[t] = v;
    __syncthreads();
    for (int off = 1; off < 256; off <<= 1) {
        int u = (t >= off) ? sh[t - off] : 0;
        __syncthreads();
        sh[t] += u;
        __syncthreads();
    }
    int excl = sh[t] - v + bsum[blockIdx.x];
    if (i < N_NODES) {
        ptrb[i] = excl;
        dinv[i] = rsqrtf((float)v);   // deg >= 1 (self loop)
    }
    if (i == N_NODES - 1) ptrb[N_NODES] = excl + v;
}

__global__ __launch_bounds__(256) void bucket(const int* __restrict__ erow,
                                              const int* __restrict__ ecol,
                                              const int* __restrict__ ptrb,
                                              int* __restrict__ fill,
                                              const float* __restrict__ dinv,
                                              int* __restrict__ esrc,
                                              int2* __restrict__ epack) {
    int e = blockIdx.x * 256 + threadIdx.x;
    if (e >= ET) return;
    int r, c;
    if (e < E_EDGES) { r = erow[e]; c = ecol[e]; }
    else             { r = e - E_EDGES; c = r; }
    int pos = ptrb[c] + atomicAdd(&fill[c], 1);
    esrc[pos]  = r;
    epack[pos] = make_int2(r, __float_as_int(dinv[r] * dinv[c]));
}

// ---------------- GEMMs (f32, vector ALU; no fp32 MFMA on CDNA4) ----------------

// C[N,128] = A[N,128] @ W[128,128].  128 rows/block, K in 2 chunks of 64.
__global__ __launch_bounds__(256, 2) void gemm128(const float* __restrict__ A,
                                                  const float* __restrict__ W,
                                                  float* __restrict__ C) {
    __shared__ float At[64 * 128];   // [kk][r]
    __shared__ float Wl[64 * 128];   // [kk][c]
    int tid  = threadIdx.x;
    int row0 = blockIdx.x * 128;
    int tx = tid & 15;               // c0 = tx*8
    int ty = tid >> 4;               // r0 = ty*8
    float acc[8][8];
#pragma unroll
    for (int i = 0; i < 8; ++i)
#pragma unroll
        for (int j = 0; j < 8; ++j) acc[i][j] = 0.f;

    const int r_ld  = tid >> 1;
    const int kb_ld = (tid & 1) * 32;
    const int wk_ld = tid >> 2;
    const int wc_ld = (tid & 3) * 32;

    for (int kc = 0; kc < 2; ++kc) {
        int gr = row0 + r_ld;
#pragma unroll
        for (int i = 0; i < 8; ++i) {
            int kl = kb_ld + i * 4;
            float4 v = make_float4(0.f, 0.f, 0.f, 0.f);
            if (gr < N_NODES)
                v = *(const float4*)(A + (size_t)gr * 128 + kc * 64 + kl);
            At[(kl + 0) * 128 + r_ld] = v.x;
            At[(kl + 1) * 128 + r_ld] = v.y;
            At[(kl + 2) * 128 + r_ld] = v.z;
            At[(kl + 3) * 128 + r_ld] = v.w;
        }
#pragma unroll
        for (int i = 0; i < 8; ++i) {
            *(float4*)(Wl + wk_ld * 128 + wc_ld + 4 * i) =
                *(const float4*)(W + (size_t)(kc * 64 + wk_ld) * 128 + wc_ld + 4 * i);
        }
        __syncthreads();
#pragma unroll 2
        for (int kk = 0; kk < 64; ++kk) {
            float4 a0 = *(float4*)(At + kk * 128 + ty * 8);
            float4 a1 = *(float4*)(At + kk * 128 + ty * 8 + 4);
            float4 w0 = *(float4*)(Wl + kk * 128 + tx * 8);
            float4 w1 = *(float4*)(Wl + kk * 128 + tx * 8 + 4);
            float av[8] = {a0.x, a0.y, a0.z, a0.w, a1.x, a1.y, a1.z, a1.w};
            float wv[8] = {w0.x, w0.y, w0.z, w0.w, w1.x, w1.y, w1.z, w1.w};
#pragma unroll
            for (int i = 0; i < 8; ++i)
#pragma unroll
                for (int j = 0; j < 8; ++j) acc[i][j] += av[i] * wv[j];
        }
        __syncthreads();
    }
#pragma unroll
    for (int i = 0; i < 8; ++i) {
        int gr = row0 + ty * 8 + i;
        if (gr < N_NODES) {
            float4 o0 = make_float4(acc[i][0], acc[i][1], acc[i][2], acc[i][3]);
            float4 o1 = make_float4(acc[i][4], acc[i][5], acc[i][6], acc[i][7]);
            *(float4*)(C + (size_t)gr * 128 + tx * 8)     = o0;
            *(float4*)(C + (size_t)gr * 128 + tx * 8 + 4) = o1;
        }
    }
}

// Dual C1=A@W1+b1, C2=A@W2+b2 (shared A staging) + fused ta[r] = C2[r,:]@avec.
__global__ __launch_bounds__(256, 2) void gemm64_dual(const float* __restrict__ A,
                                                      const float* __restrict__ W1,
                                                      const float* __restrict__ b1,
                                                      const float* __restrict__ W2,
                                                      const float* __restrict__ b2,
                                                      const float* __restrict__ avec,
                                                      float* __restrict__ C1,
                                                      float* __restrict__ C2,
                                                      float* __restrict__ ta) {
    __shared__ float At[64 * 128];   // [k][r]  32KB
    __shared__ float W1l[64 * 64];   // 16KB
    __shared__ float W2l[64 * 64];   // 16KB
    int tid  = threadIdx.x;
    int row0 = blockIdx.x * 128;
    int tx = tid & 7;                // c0 = tx*8
    int ty = tid >> 3;               // r0 = ty*4 (ty 0..31)
    float acc1[4][8], acc2[4][8];
#pragma unroll
    for (int i = 0; i < 4; ++i)
#pragma unroll
        for (int j = 0; j < 8; ++j) { acc1[i][j] = 0.f; acc2[i][j] = 0.f; }

    {
        int r_ld  = tid >> 1;
        int kb_ld = (tid & 1) * 32;
        int gr = row0 + r_ld;
#pragma unroll
        for (int i = 0; i < 8; ++i) {
            int kl = kb_ld + i * 4;
            float4 v = make_float4(0.f, 0.f, 0.f, 0.f);
            if (gr < N_NODES) v = *(const float4*)(A + (size_t)gr * 64 + kl);
            At[(kl + 0) * 128 + r_ld] = v.x;
            At[(kl + 1) * 128 + r_ld] = v.y;
            At[(kl + 2) * 128 + r_ld] = v.z;
            At[(kl + 3) * 128 + r_ld] = v.w;
        }
        int wk = tid >> 2;
        int wc = (tid & 3) * 16;
#pragma unroll
        for (int i = 0; i < 4; ++i) {
            *(float4*)(W1l + wk * 64 + wc + 4 * i) =
                *(const float4*)(W1 + (size_t)wk * 64 + wc + 4 * i);
            *(float4*)(W2l + wk * 64 + wc + 4 * i) =
                *(const float4*)(W2 + (size_t)wk * 64 + wc + 4 * i);
        }
    }
    __syncthreads();
#pragma unroll 2
    for (int k = 0; k < 64; ++k) {
        float4 a0 = *(float4*)(At + k * 128 + ty * 4);
        float4 u0 = *(float4*)(W1l + k * 64 + tx * 8);
        float4 u1 = *(float4*)(W1l + k * 64 + tx * 8 + 4);
        float4 v0 = *(float4*)(W2l + k * 64 + tx * 8);
        float4 v1 = *(float4*)(W2l + k * 64 + tx * 8 + 4);
        float av[4] = {a0.x, a0.y, a0.z, a0.w};
        float w1v[8] = {u0.x, u0.y, u0.z, u0.w, u1.x, u1.y, u1.z, u1.w};
        float w2v[8] = {v0.x, v0.y, v0.z, v0.w, v1.x, v1.y, v1.z, v1.w};
#pragma unroll
        for (int i = 0; i < 4; ++i)
#pragma unroll
            for (int j = 0; j < 8; ++j) {
                acc1[i][j] += av[i] * w1v[j];
                acc2[i][j] += av[i] * w2v[j];
            }
    }
    float b1j[8], b2j[8], aj[8];
#pragma unroll
    for (int j = 0; j < 8; ++j) {
        b1j[j] = b1[tx * 8 + j];
        b2j[j] = b2[tx * 8 + j];
        aj[j]  = avec[tx * 8 + j];
    }
#pragma unroll
    for (int i = 0; i < 4; ++i) {
        int gr = row0 + ty * 4 + i;
        float t2[8];
        float pa = 0.f;
#pragma unroll
        for (int j = 0; j < 8; ++j) {
            t2[j] = acc2[i][j] + b2j[j];
            pa += t2[j] * aj[j];
        }
        // reduce pa across the 8 tx lanes (consecutive lanes in wave)
        pa += __shfl_xor(pa, 1);
        pa += __shfl_xor(pa, 2);
        pa += __shfl_xor(pa, 4);
        if (gr < N_NODES) {
            float4 o0 = make_float4(acc1[i][0] + b1j[0], acc1[i][1] + b1j[1],
                                    acc1[i][2] + b1j[2], acc1[i][3] + b1j[3]);
            float4 o1 = make_float4(acc1[i][4] + b1j[4], acc1[i][5] + b1j[5],
                                    acc1[i][6] + b1j[6], acc1[i][7] + b1j[7]);
            *(float4*)(C1 + (size_t)gr * 64 + tx * 8)     = o0;
            *(float4*)(C1 + (size_t)gr * 64 + tx * 8 + 4) = o1;
            float4 p0 = make_float4(t2[0], t2[1], t2[2], t2[3]);
            float4 p1 = make_float4(t2[4], t2[5], t2[6], t2[7]);
            *(float4*)(C2 + (size_t)gr * 64 + tx * 8)     = p0;
            *(float4*)(C2 + (size_t)gr * 64 + tx * 8 + 4) = p1;
            if (tx == 0) ta[gr] = pa;
        }
    }
}

// ---------------- edge aggregation (one wave per dst) ----------------

// lane = {sub: bit5, fl: bits0-4}; 32 lanes x float4 = 128 features, 2 edge slots
__global__ __launch_bounds__(256) void agg128(const float* __restrict__ h2,
                                              const int* __restrict__ ptrb,
                                              const int2* __restrict__ epack,
                                              const float* __restrict__ bias,
                                              float* __restrict__ out,
                                              int apply_gelu) {
    int dst  = (blockIdx.x * 256 + threadIdx.x) >> 6;
    int lane = threadIdx.x & 63;
    if (dst >= N_NODES) return;
    int sub = lane >> 5;
    int fl  = lane & 31;
    int p0 = ptrb[dst], p1 = ptrb[dst + 1];
    float4 acc = make_float4(0.f, 0.f, 0.f, 0.f);
    for (int p = p0 + sub; p < p1; p += 2) {
        int2 ed = epack[p];
        float nv = __int_as_float(ed.y);
        float4 v = *(const float4*)(h2 + (size_t)ed.x * 128 + fl * 4);
        acc.x += nv * v.x; acc.y += nv * v.y;
        acc.z += nv * v.z; acc.w += nv * v.w;
    }
    acc.x += __shfl_xor(acc.x, 32);
    acc.y += __shfl_xor(acc.y, 32);
    acc.z += __shfl_xor(acc.z, 32);
    acc.w += __shfl_xor(acc.w, 32);
    if (sub == 0) {
        float4 b4 = *(const float4*)(bias + fl * 4);
        float v0 = acc.x + b4.x, v1 = acc.y + b4.y;
        float v2 = acc.z + b4.z, v3 = acc.w + b4.w;
        if (apply_gelu) {
            v0 = gelu_f(v0); v1 = gelu_f(v1); v2 = gelu_f(v2); v3 = gelu_f(v3);
        }
        *(float4*)(out + (size_t)dst * 128 + fl * 4) = make_float4(v0, v1, v2, v3);
    }
}

// lane = {sub: bits4-5, fl: bits0-3}; 16 lanes x float4 = 64 features, 4 edge slots
__global__ __launch_bounds__(256) void gna_agg(const float* __restrict__ t,
                                               const float* __restrict__ ta,
                                               const int* __restrict__ ptrb,
                                               const int* __restrict__ esrc,
                                               const float* __restrict__ base,
                                               float* __restrict__ gout) {
    int dst  = (blockIdx.x * 256 + threadIdx.x) >> 6;
    int lane = threadIdx.x & 63;
    if (dst >= N_NODES) return;
    int p0 = ptrb[dst], p1 = ptrb[dst + 1];
    float tac = ta[dst];
    // pass 1: segment max of alpha = tac - ta[src]
    float m = -1e30f;
    for (int p = p0 + lane; p < p1; p += 64) m = fmaxf(m, tac - ta[esrc[p]]);
#pragma unroll
    for (int off = 32; off; off >>= 1) m = fmaxf(m, __shfl_xor(m, off));
    // pass 2: denom
    float ssum = 0.f;
    for (int p = p0 + lane; p < p1; p += 64) ssum += expf(tac - ta[esrc[p]] - m);
#pragma unroll
    for (int off = 32; off; off >>= 1) ssum += __shfl_xor(ssum, off);
    float winv = 1.0f / (ssum + 1e-16f);
    // pass 3: weighted message; winv factored out of the loop
    int sub = lane >> 4;
    int fl  = lane & 15;
    float4 macc = make_float4(0.f, 0.f, 0.f, 0.f);
    for (int p = p0 + sub; p < p1; p += 4) {
        int src = esrc[p];
        float w = expf(tac - ta[src] - m);
        float4 v = *(const float4*)(t + (size_t)src * 64 + fl * 4);
        macc.x += w * v.x; macc.y += w * v.y;
        macc.z += w * v.z; macc.w += w * v.w;
    }
#pragma unroll
    for (int off = 16; off <= 32; off <<= 1) {
        macc.x += __shfl_xor(macc.x, off);
        macc.y += __shfl_xor(macc.y, off);
        macc.z += __shfl_xor(macc.z, off);
        macc.w += __shfl_xor(macc.w, off);
    }
    if (lane < 16) {
        float4 bs = *(const float4*)(base + (size_t)dst * 64 + fl * 4);
        float v0 = bs.x + macc.x * winv;
        float v1 = bs.y + macc.y * winv;
        float v2 = bs.z + macc.z * winv;
        float v3 = bs.w + macc.w * winv;
        *(float4*)(gout + (size_t)dst * 64 + fl * 4) =
            make_float4(gelu_f(v0), gelu_f(v1), gelu_f(v2), gelu_f(v3));
    }
}

// ---------------- launch ----------------

extern "C" void kernel_launch(void* const* d_in, const int* in_sizes, int n_in,
                              void* d_out, int out_size, void* d_ws, size_t ws_size,
                              hipStream_t stream) {
    const float* x     = (const float*)d_in[0];
    const float* s     = (const float*)d_in[1];
    const int*   ei    = (const int*)d_in[2];
    const float* gcn_W = (const float*)d_in[3];
    const float* gcn_b = (const float*)d_in[4];
    const float* w1W   = (const float*)d_in[5];
    const float* w1b   = (const float*)d_in[6];
    const float* w2W   = (const float*)d_in[7];
    const float* w2b   = (const float*)d_in[8];
    const float* ga    = (const float*)d_in[9];

    float* h_out = (float*)d_out;                               // N x 128
    float* g_out = (float*)d_out + (size_t)N_NODES * 128;       // N x 64

    size_t off = 0;
    char* wsb = (char*)d_ws;
    auto take = [&](size_t bytes) {
        void* p = wsb + off;
        off = (off + bytes + 255) & ~(size_t)255;
        return p;
    };
    int*   cnt     = (int*)take((size_t)N_NODES * 4);
    int*   ptrb    = (int*)take((size_t)(N_NODES + 1) * 4);
    int*   fill    = (int*)take((size_t)N_NODES * 4);
    int*   esrc    = (int*)take((size_t)ET * 4);
    float* dinv    = (float*)take((size_t)N_NODES * 4);
    int2*  epack   = (int2*)take((size_t)ET * 8);
    float* h2      = (float*)take((size_t)N_NODES * 128 * 4);
    float* tbuf    = (float*)take((size_t)N_NODES * 64 * 4);
    float* basebuf = (float*)take((size_t)N_NODES * 64 * 4);
    float* tabuf   = (float*)take((size_t)N_NODES * 4);
    int*   bsum    = (int*)take((size_t)NB_SCAN * 4);
    (void)ws_size; (void)in_sizes; (void)n_in; (void)out_size;

    const int* erow = ei;
    const int* ecol = ei + E_EDGES;

    hipMemsetAsync(cnt, 0, (size_t)N_NODES * 4, stream);
    hipMemsetAsync(fill, 0, (size_t)N_NODES * 4, stream);

    int ge = (ET + 255) / 256;
    count_deg<<<ge, 256, 0, stream>>>(ecol, cnt);
    scan_part1<<<NB_SCAN, 256, 0, stream>>>(cnt, bsum);
    scan_part2<<<1, 256, 0, stream>>>(bsum);
    scan_part3<<<NB_SCAN, 256, 0, stream>>>(cnt, bsum, ptrb, dinv);
    bucket<<<ge, 256, 0, stream>>>(erow, ecol, ptrb, fill, dinv, esrc, epack);

    const int gemm_blocks = (N_NODES + 127) / 128;       // 391
    const int wave_blocks = (N_NODES * 64 + 255) / 256;  // 12500

    // ---- GCN ----
    const float* hin = x;
    for (int l = 0; l < L_LAYERS; ++l) {
        gemm128<<<gemm_blocks, 256, 0, stream>>>(hin, gcn_W + (size_t)l * 128 * 128, h2);
        agg128<<<wave_blocks, 256, 0, stream>>>(h2, ptrb, epack,
                                                gcn_b + (size_t)l * 128, h_out,
                                                (l < L_LAYERS - 1) ? 1 : 0);
        hin = h_out;
    }

    // ---- GNA ----
    const float* gin = s;
    for (int l = 0; l < L_LAYERS; ++l) {
        gemm64_dual<<<gemm_blocks, 256, 0, stream>>>(
            gin,
            w1W + (size_t)l * 64 * 64, w1b + (size_t)l * 64,
            w2W + (size_t)l * 64 * 64, w2b + (size_t)l * 64,
            ga + (size_t)l * 64,
            basebuf, tbuf, tabuf);
        gna_agg<<<wave_blocks, 256, 0, stream>>>(tbuf, tabuf, ptrb, esrc, basebuf, g_out);
        gin = g_out;
    }
}

// Round 3
// 787.188 us; speedup vs baseline: 1.6957x; 1.0894x over previous
//
#include <hip/hip_runtime.h>
#include <math.h>

#define N_NODES 50000
#define E_EDGES 800000
#define ET (E_EDGES + N_NODES)   // edges + self loops
#define L_LAYERS 4
#define NB_SCAN ((N_NODES + 255) / 256)   // 196

__device__ __forceinline__ float gelu_f(float x) {
    return 0.5f * x * (1.0f + erff(x * 0.70710678118654752f));
}

// ---------------- graph preprocessing ----------------

// counts degree AND records each edge's position within its dst bucket
// (the atomicAdd return value) so the bucket pass needs no atomics.
__global__ __launch_bounds__(256) void count_pos(const int* __restrict__ ecol,
                                                 int* __restrict__ cnt,
                                                 int* __restrict__ aux) {
    int e = blockIdx.x * 256 + threadIdx.x;
    if (e >= ET) return;
    int c = (e < E_EDGES) ? ecol[e] : (e - E_EDGES);
    aux[e] = atomicAdd(&cnt[c], 1);
}

// phase 1: per-block reduce of cnt
__global__ __launch_bounds__(256) void scan_part1(const int* __restrict__ cnt,
                                                  int* __restrict__ bsum) {
    __shared__ int red[256];
    int t = threadIdx.x;
    int i = blockIdx.x * 256 + t;
    red[t] = (i < N_NODES) ? cnt[i] : 0;
    __syncthreads();
#pragma unroll
    for (int off = 128; off; off >>= 1) {
        if (t < off) red[t] += red[t + off];
        __syncthreads();
    }
    if (t == 0) bsum[blockIdx.x] = red[0];
}

// phase 2: exclusive scan of the 196 block sums (single tiny block)
__global__ __launch_bounds__(256) void scan_part2(int* __restrict__ bsum) {
    __shared__ int sh[256];
    int t = threadIdx.x;
    int v = (t < NB_SCAN) ? bsum[t] : 0;
    sh[t] = v;
    __syncthreads();
    for (int off = 1; off < 256; off <<= 1) {
        int u = (t >= off) ? sh[t - off] : 0;
        __syncthreads();
        sh[t] += u;
        __syncthreads();
    }
    if (t < NB_SCAN) bsum[t] = sh[t] - v;   // exclusive
}

// phase 3: per-block exclusive rescan + offset; also emits dinv
__global__ __launch_bounds__(256) void scan_part3(const int* __restrict__ cnt,
                                                  const int* __restrict__ bsum,
                                                  int* __restrict__ ptrb,
                                                  float* __restrict__ dinv) {
    __shared__ int sh[256];
    int t = threadIdx.x;
    int i = blockIdx.x * 256 + t;
    int v = (i < N_NODES) ? cnt[i] : 0;
    sh[t] = v;
    __syncthreads();
    for (int off = 1; off < 256; off <<= 1) {
        int u = (t >= off) ? sh[t - off] : 0;
        __syncthreads();
        sh[t] += u;
        __syncthreads();
    }
    int excl = sh[t] - v + bsum[blockIdx.x];
    if (i < N_NODES) {
        ptrb[i] = excl;
        dinv[i] = rsqrtf((float)v);   // deg >= 1 (self loop)
    }
    if (i == N_NODES - 1) ptrb[N_NODES] = excl + v;
}

// atomic-free scatter: pos = ptrb[dst] + aux[e]; single 8B write per edge
__global__ __launch_bounds__(256) void bucket(const int* __restrict__ erow,
                                              const int* __restrict__ ecol,
                                              const int* __restrict__ aux,
                                              const int* __restrict__ ptrb,
                                              const float* __restrict__ dinv,
                                              int2* __restrict__ epack) {
    int e = blockIdx.x * 256 + threadIdx.x;
    if (e >= ET) return;
    int r, c;
    if (e < E_EDGES) { r = erow[e]; c = ecol[e]; }
    else             { r = e - E_EDGES; c = r; }
    int pos = ptrb[c] + aux[e];
    epack[pos] = make_int2(r, __float_as_int(dinv[r] * dinv[c]));
}

// ---------------- GEMMs (f32, vector ALU; no fp32 MFMA on CDNA4) ----------------

// C[N,128] = A[N,128] @ W[128,128].  128 rows/block, K in 2 chunks of 64.
__global__ __launch_bounds__(256, 2) void gemm128(const float* __restrict__ A,
                                                  const float* __restrict__ W,
                                                  float* __restrict__ C) {
    __shared__ float At[64 * 128];   // [kk][r]
    __shared__ float Wl[64 * 128];   // [kk][c]
    int tid  = threadIdx.x;
    int row0 = blockIdx.x * 128;
    int tx = tid & 15;               // c0 = tx*8
    int ty = tid >> 4;               // r0 = ty*8
    float acc[8][8];
#pragma unroll
    for (int i = 0; i < 8; ++i)
#pragma unroll
        for (int j = 0; j < 8; ++j) acc[i][j] = 0.f;

    const int r_ld  = tid >> 1;
    const int kb_ld = (tid & 1) * 32;
    const int wk_ld = tid >> 2;
    const int wc_ld = (tid & 3) * 32;

    for (int kc = 0; kc < 2; ++kc) {
        int gr = row0 + r_ld;
#pragma unroll
        for (int i = 0; i < 8; ++i) {
            int kl = kb_ld + i * 4;
            float4 v = make_float4(0.f, 0.f, 0.f, 0.f);
            if (gr < N_NODES)
                v = *(const float4*)(A + (size_t)gr * 128 + kc * 64 + kl);
            At[(kl + 0) * 128 + r_ld] = v.x;
            At[(kl + 1) * 128 + r_ld] = v.y;
            At[(kl + 2) * 128 + r_ld] = v.z;
            At[(kl + 3) * 128 + r_ld] = v.w;
        }
#pragma unroll
        for (int i = 0; i < 8; ++i) {
            *(float4*)(Wl + wk_ld * 128 + wc_ld + 4 * i) =
                *(const float4*)(W + (size_t)(kc * 64 + wk_ld) * 128 + wc_ld + 4 * i);
        }
        __syncthreads();
#pragma unroll 2
        for (int kk = 0; kk < 64; ++kk) {
            float4 a0 = *(float4*)(At + kk * 128 + ty * 8);
            float4 a1 = *(float4*)(At + kk * 128 + ty * 8 + 4);
            float4 w0 = *(float4*)(Wl + kk * 128 + tx * 8);
            float4 w1 = *(float4*)(Wl + kk * 128 + tx * 8 + 4);
            float av[8] = {a0.x, a0.y, a0.z, a0.w, a1.x, a1.y, a1.z, a1.w};
            float wv[8] = {w0.x, w0.y, w0.z, w0.w, w1.x, w1.y, w1.z, w1.w};
#pragma unroll
            for (int i = 0; i < 8; ++i)
#pragma unroll
                for (int j = 0; j < 8; ++j) acc[i][j] += av[i] * wv[j];
        }
        __syncthreads();
    }
#pragma unroll
    for (int i = 0; i < 8; ++i) {
        int gr = row0 + ty * 8 + i;
        if (gr < N_NODES) {
            float4 o0 = make_float4(acc[i][0], acc[i][1], acc[i][2], acc[i][3]);
            float4 o1 = make_float4(acc[i][4], acc[i][5], acc[i][6], acc[i][7]);
            *(float4*)(C + (size_t)gr * 128 + tx * 8)     = o0;
            *(float4*)(C + (size_t)gr * 128 + tx * 8 + 4) = o1;
        }
    }
}

// Dual C1=A@W1+b1, C2=A@W2+b2 (shared A staging) + fused ta[r] = C2[r,:]@avec.
__global__ __launch_bounds__(256, 2) void gemm64_dual(const float* __restrict__ A,
                                                      const float* __restrict__ W1,
                                                      const float* __restrict__ b1,
                                                      const float* __restrict__ W2,
                                                      const float* __restrict__ b2,
                                                      const float* __restrict__ avec,
                                                      float* __restrict__ C1,
                                                      float* __restrict__ C2,
                                                      float* __restrict__ ta) {
    __shared__ float At[64 * 128];   // [k][r]  32KB
    __shared__ float W1l[64 * 64];   // 16KB
    __shared__ float W2l[64 * 64];   // 16KB
    int tid  = threadIdx.x;
    int row0 = blockIdx.x * 128;
    int tx = tid & 7;                // c0 = tx*8
    int ty = tid >> 3;               // r0 = ty*4 (ty 0..31)
    float acc1[4][8], acc2[4][8];
#pragma unroll
    for (int i = 0; i < 4; ++i)
#pragma unroll
        for (int j = 0; j < 8; ++j) { acc1[i][j] = 0.f; acc2[i][j] = 0.f; }

    {
        int r_ld  = tid >> 1;
        int kb_ld = (tid & 1) * 32;
        int gr = row0 + r_ld;
#pragma unroll
        for (int i = 0; i < 8; ++i) {
            int kl = kb_ld + i * 4;
            float4 v = make_float4(0.f, 0.f, 0.f, 0.f);
            if (gr < N_NODES) v = *(const float4*)(A + (size_t)gr * 64 + kl);
            At[(kl + 0) * 128 + r_ld] = v.x;
            At[(kl + 1) * 128 + r_ld] = v.y;
            At[(kl + 2) * 128 + r_ld] = v.z;
            At[(kl + 3) * 128 + r_ld] = v.w;
        }
        int wk = tid >> 2;
        int wc = (tid & 3) * 16;
#pragma unroll
        for (int i = 0; i < 4; ++i) {
            *(float4*)(W1l + wk * 64 + wc + 4 * i) =
                *(const float4*)(W1 + (size_t)wk * 64 + wc + 4 * i);
            *(float4*)(W2l + wk * 64 + wc + 4 * i) =
                *(const float4*)(W2 + (size_t)wk * 64 + wc + 4 * i);
        }
    }
    __syncthreads();
#pragma unroll 2
    for (int k = 0; k < 64; ++k) {
        float4 a0 = *(float4*)(At + k * 128 + ty * 4);
        float4 u0 = *(float4*)(W1l + k * 64 + tx * 8);
        float4 u1 = *(float4*)(W1l + k * 64 + tx * 8 + 4);
        float4 v0 = *(float4*)(W2l + k * 64 + tx * 8);
        float4 v1 = *(float4*)(W2l + k * 64 + tx * 8 + 4);
        float av[4] = {a0.x, a0.y, a0.z, a0.w};
        float w1v[8] = {u0.x, u0.y, u0.z, u0.w, u1.x, u1.y, u1.z, u1.w};
        float w2v[8] = {v0.x, v0.y, v0.z, v0.w, v1.x, v1.y, v1.z, v1.w};
#pragma unroll
        for (int i = 0; i < 4; ++i)
#pragma unroll
            for (int j = 0; j < 8; ++j) {
                acc1[i][j] += av[i] * w1v[j];
                acc2[i][j] += av[i] * w2v[j];
            }
    }
    float b1j[8], b2j[8], aj[8];
#pragma unroll
    for (int j = 0; j < 8; ++j) {
        b1j[j] = b1[tx * 8 + j];
        b2j[j] = b2[tx * 8 + j];
        aj[j]  = avec[tx * 8 + j];
    }
#pragma unroll
    for (int i = 0; i < 4; ++i) {
        int gr = row0 + ty * 4 + i;
        float t2[8];
        float pa = 0.f;
#pragma unroll
        for (int j = 0; j < 8; ++j) {
            t2[j] = acc2[i][j] + b2j[j];
            pa += t2[j] * aj[j];
        }
        pa += __shfl_xor(pa, 1);
        pa += __shfl_xor(pa, 2);
        pa += __shfl_xor(pa, 4);
        if (gr < N_NODES) {
            float4 o0 = make_float4(acc1[i][0] + b1j[0], acc1[i][1] + b1j[1],
                                    acc1[i][2] + b1j[2], acc1[i][3] + b1j[3]);
            float4 o1 = make_float4(acc1[i][4] + b1j[4], acc1[i][5] + b1j[5],
                                    acc1[i][6] + b1j[6], acc1[i][7] + b1j[7]);
            *(float4*)(C1 + (size_t)gr * 64 + tx * 8)     = o0;
            *(float4*)(C1 + (size_t)gr * 64 + tx * 8 + 4) = o1;
            float4 p0 = make_float4(t2[0], t2[1], t2[2], t2[3]);
            float4 p1 = make_float4(t2[4], t2[5], t2[6], t2[7]);
            *(float4*)(C2 + (size_t)gr * 64 + tx * 8)     = p0;
            *(float4*)(C2 + (size_t)gr * 64 + tx * 8 + 4) = p1;
            if (tx == 0) ta[gr] = pa;
        }
    }
}

// ---------------- edge aggregation (one wave per dst) ----------------

// lane = {sub: bit5, fl: bits0-4}; 32 lanes x float4 = 128 features, 2 edge slots
__global__ __launch_bounds__(256) void agg128(const float* __restrict__ h2,
                                              const int* __restrict__ ptrb,
                                              const int2* __restrict__ epack,
                                              const float* __restrict__ bias,
                                              float* __restrict__ out,
                                              int apply_gelu) {
    int dst  = (blockIdx.x * 256 + threadIdx.x) >> 6;
    int lane = threadIdx.x & 63;
    if (dst >= N_NODES) return;
    int sub = lane >> 5;
    int fl  = lane & 31;
    int p0 = ptrb[dst], p1 = ptrb[dst + 1];
    float4 acc = make_float4(0.f, 0.f, 0.f, 0.f);
    for (int p = p0 + sub; p < p1; p += 2) {
        int2 ed = epack[p];
        float nv = __int_as_float(ed.y);
        float4 v = *(const float4*)(h2 + (size_t)ed.x * 128 + fl * 4);
        acc.x += nv * v.x; acc.y += nv * v.y;
        acc.z += nv * v.z; acc.w += nv * v.w;
    }
    acc.x += __shfl_xor(acc.x, 32);
    acc.y += __shfl_xor(acc.y, 32);
    acc.z += __shfl_xor(acc.z, 32);
    acc.w += __shfl_xor(acc.w, 32);
    if (sub == 0) {
        float4 b4 = *(const float4*)(bias + fl * 4);
        float v0 = acc.x + b4.x, v1 = acc.y + b4.y;
        float v2 = acc.z + b4.z, v3 = acc.w + b4.w;
        if (apply_gelu) {
            v0 = gelu_f(v0); v1 = gelu_f(v1); v2 = gelu_f(v2); v3 = gelu_f(v3);
        }
        *(float4*)(out + (size_t)dst * 128 + fl * 4) = make_float4(v0, v1, v2, v3);
    }
}

// single pass: softmax max-shift is redundant here (|alpha| bounded << 80),
// and denom + weighted message accumulate together:
//   msg = sum(e * t[src]) / (sum(e) + 1e-16),  e = exp(ta[dst]-ta[src])
// lane = {sub: bits4-5, fl: bits0-3}; 16 lanes x float4 = 64 features, 4 edge slots
__global__ __launch_bounds__(256) void gna_agg(const float* __restrict__ t,
                                               const float* __restrict__ ta,
                                               const int* __restrict__ ptrb,
                                               const int2* __restrict__ epack,
                                               const float* __restrict__ base,
                                               float* __restrict__ gout) {
    int dst  = (blockIdx.x * 256 + threadIdx.x) >> 6;
    int lane = threadIdx.x & 63;
    if (dst >= N_NODES) return;
    int p0 = ptrb[dst], p1 = ptrb[dst + 1];
    float tac = ta[dst];
    int sub = lane >> 4;
    int fl  = lane & 15;
    float se = 0.f;
    float4 macc = make_float4(0.f, 0.f, 0.f, 0.f);
    for (int p = p0 + sub; p < p1; p += 4) {
        int src = epack[p].x;
        float e = expf(tac - ta[src]);
        float4 v = *(const float4*)(t + (size_t)src * 64 + fl * 4);
        se     += e;
        macc.x += e * v.x; macc.y += e * v.y;
        macc.z += e * v.z; macc.w += e * v.w;
    }
#pragma unroll
    for (int off = 16; off <= 32; off <<= 1) {
        se     += __shfl_xor(se, off);
        macc.x += __shfl_xor(macc.x, off);
        macc.y += __shfl_xor(macc.y, off);
        macc.z += __shfl_xor(macc.z, off);
        macc.w += __shfl_xor(macc.w, off);
    }
    if (lane < 16) {
        float winv = 1.0f / (se + 1e-16f);
        float4 bs = *(const float4*)(base + (size_t)dst * 64 + fl * 4);
        float v0 = bs.x + macc.x * winv;
        float v1 = bs.y + macc.y * winv;
        float v2 = bs.z + macc.z * winv;
        float v3 = bs.w + macc.w * winv;
        *(float4*)(gout + (size_t)dst * 64 + fl * 4) =
            make_float4(gelu_f(v0), gelu_f(v1), gelu_f(v2), gelu_f(v3));
    }
}

// ---------------- launch ----------------

extern "C" void kernel_launch(void* const* d_in, const int* in_sizes, int n_in,
                              void* d_out, int out_size, void* d_ws, size_t ws_size,
                              hipStream_t stream) {
    const float* x     = (const float*)d_in[0];
    const float* s     = (const float*)d_in[1];
    const int*   ei    = (const int*)d_in[2];
    const float* gcn_W = (const float*)d_in[3];
    const float* gcn_b = (const float*)d_in[4];
    const float* w1W   = (const float*)d_in[5];
    const float* w1b   = (const float*)d_in[6];
    const float* w2W   = (const float*)d_in[7];
    const float* w2b   = (const float*)d_in[8];
    const float* ga    = (const float*)d_in[9];

    float* h_out = (float*)d_out;                               // N x 128
    float* g_out = (float*)d_out + (size_t)N_NODES * 128;       // N x 64

    size_t off = 0;
    char* wsb = (char*)d_ws;
    auto take = [&](size_t bytes) {
        void* p = wsb + off;
        off = (off + bytes + 255) & ~(size_t)255;
        return p;
    };
    int*   cnt     = (int*)take((size_t)N_NODES * 4);
    int*   ptrb    = (int*)take((size_t)(N_NODES + 1) * 4);
    int*   aux     = (int*)take((size_t)ET * 4);
    float* dinv    = (float*)take((size_t)N_NODES * 4);
    int2*  epack   = (int2*)take((size_t)ET * 8);
    float* h2      = (float*)take((size_t)N_NODES * 128 * 4);
    float* tbuf    = (float*)take((size_t)N_NODES * 64 * 4);
    float* basebuf = (float*)take((size_t)N_NODES * 64 * 4);
    float* tabuf   = (float*)take((size_t)N_NODES * 4);
    int*   bsum    = (int*)take((size_t)NB_SCAN * 4);
    (void)ws_size; (void)in_sizes; (void)n_in; (void)out_size;

    const int* erow = ei;
    const int* ecol = ei + E_EDGES;

    hipMemsetAsync(cnt, 0, (size_t)N_NODES * 4, stream);

    int ge = (ET + 255) / 256;
    count_pos<<<ge, 256, 0, stream>>>(ecol, cnt, aux);
    scan_part1<<<NB_SCAN, 256, 0, stream>>>(cnt, bsum);
    scan_part2<<<1, 256, 0, stream>>>(bsum);
    scan_part3<<<NB_SCAN, 256, 0, stream>>>(cnt, bsum, ptrb, dinv);
    bucket<<<ge, 256, 0, stream>>>(erow, ecol, aux, ptrb, dinv, epack);

    const int gemm_blocks = (N_NODES + 127) / 128;       // 391
    const int wave_blocks = (N_NODES * 64 + 255) / 256;  // 12500

    // ---- GCN ----
    const float* hin = x;
    for (int l = 0; l < L_LAYERS; ++l) {
        gemm128<<<gemm_blocks, 256, 0, stream>>>(hin, gcn_W + (size_t)l * 128 * 128, h2);
        agg128<<<wave_blocks, 256, 0, stream>>>(h2, ptrb, epack,
                                                gcn_b + (size_t)l * 128, h_out,
                                                (l < L_LAYERS - 1) ? 1 : 0);
        hin = h_out;
    }

    // ---- GNA ----
    const float* gin = s;
    for (int l = 0; l < L_LAYERS; ++l) {
        gemm64_dual<<<gemm_blocks, 256, 0, stream>>>(
            gin,
            w1W + (size_t)l * 64 * 64, w1b + (size_t)l * 64,
            w2W + (size_t)l * 64 * 64, w2b + (size_t)l * 64,
            ga + (size_t)l * 64,
            basebuf, tbuf, tabuf);
        gna_agg<<<wave_blocks, 256, 0, stream>>>(tbuf, tabuf, ptrb, epack, basebuf, g_out);
        gin = g_out;
    }
}

// Round 5
// 740.977 us; speedup vs baseline: 1.8015x; 1.0624x over previous
//
#include <hip/hip_runtime.h>
#include <math.h>

#define N_NODES 50000
#define E_EDGES 800000
#define ET (E_EDGES + N_NODES)   // edges + self loops
#define L_LAYERS 4
#define NB_SCAN ((N_NODES + 255) / 256)   // 196

__device__ __forceinline__ float gelu_f(float x) {
    return 0.5f * x * (1.0f + erff(x * 0.70710678118654752f));
}

// ---------------- graph preprocessing ----------------

// counts degree AND records each edge's position within its dst bucket
// (the atomicAdd return value) so the bucket pass needs no atomics.
__global__ __launch_bounds__(256) void count_pos(const int* __restrict__ ecol,
                                                 int* __restrict__ cnt,
                                                 int* __restrict__ aux) {
    int e = blockIdx.x * 256 + threadIdx.x;
    if (e >= ET) return;
    int c = (e < E_EDGES) ? ecol[e] : (e - E_EDGES);
    aux[e] = atomicAdd(&cnt[c], 1);
}

__global__ __launch_bounds__(256) void scan_part1(const int* __restrict__ cnt,
                                                  int* __restrict__ bsum) {
    __shared__ int red[256];
    int t = threadIdx.x;
    int i = blockIdx.x * 256 + t;
    red[t] = (i < N_NODES) ? cnt[i] : 0;
    __syncthreads();
#pragma unroll
    for (int off = 128; off; off >>= 1) {
        if (t < off) red[t] += red[t + off];
        __syncthreads();
    }
    if (t == 0) bsum[blockIdx.x] = red[0];
}

__global__ __launch_bounds__(256) void scan_part2(int* __restrict__ bsum) {
    __shared__ int sh[256];
    int t = threadIdx.x;
    int v = (t < NB_SCAN) ? bsum[t] : 0;
    sh[t] = v;
    __syncthreads();
    for (int off = 1; off < 256; off <<= 1) {
        int u = (t >= off) ? sh[t - off] : 0;
        __syncthreads();
        sh[t] += u;
        __syncthreads();
    }
    if (t < NB_SCAN) bsum[t] = sh[t] - v;   // exclusive
}

__global__ __launch_bounds__(256) void scan_part3(const int* __restrict__ cnt,
                                                  const int* __restrict__ bsum,
                                                  int* __restrict__ ptrb,
                                                  float* __restrict__ dinv) {
    __shared__ int sh[256];
    int t = threadIdx.x;
    int i = blockIdx.x * 256 + t;
    int v = (i < N_NODES) ? cnt[i] : 0;
    sh[t] = v;
    __syncthreads();
    for (int off = 1; off < 256; off <<= 1) {
        int u = (t >= off) ? sh[t - off] : 0;
        __syncthreads();
        sh[t] += u;
        __syncthreads();
    }
    int excl = sh[t] - v + bsum[blockIdx.x];
    if (i < N_NODES) {
        ptrb[i] = excl;
        dinv[i] = rsqrtf((float)v);   // deg >= 1 (self loop)
    }
    if (i == N_NODES - 1) ptrb[N_NODES] = excl + v;
}

__global__ __launch_bounds__(256) void bucket(const int* __restrict__ erow,
                                              const int* __restrict__ ecol,
                                              const int* __restrict__ aux,
                                              const int* __restrict__ ptrb,
                                              const float* __restrict__ dinv,
                                              int2* __restrict__ epack) {
    int e = blockIdx.x * 256 + threadIdx.x;
    if (e >= ET) return;
    int r, c;
    if (e < E_EDGES) { r = erow[e]; c = ecol[e]; }
    else             { r = e - E_EDGES; c = r; }
    int pos = ptrb[c] + aux[e];
    epack[pos] = make_int2(r, __float_as_int(dinv[r] * dinv[c]));
}

// ---------------- GEMMs (f32, vector ALU; no fp32 MFMA on CDNA4) ----------------

__global__ __launch_bounds__(256, 2) void gemm128(const float* __restrict__ A,
                                                  const float* __restrict__ W,
                                                  float* __restrict__ C) {
    __shared__ float At[64 * 128];   // [kk][r]
    __shared__ float Wl[64 * 128];   // [kk][c]
    int tid  = threadIdx.x;
    int row0 = blockIdx.x * 128;
    int tx = tid & 15;               // c0 = tx*8
    int ty = tid >> 4;               // r0 = ty*8
    float acc[8][8];
#pragma unroll
    for (int i = 0; i < 8; ++i)
#pragma unroll
        for (int j = 0; j < 8; ++j) acc[i][j] = 0.f;

    const int r_ld  = tid >> 1;
    const int kb_ld = (tid & 1) * 32;
    const int wk_ld = tid >> 2;
    const int wc_ld = (tid & 3) * 32;

    for (int kc = 0; kc < 2; ++kc) {
        int gr = row0 + r_ld;
#pragma unroll
        for (int i = 0; i < 8; ++i) {
            int kl = kb_ld + i * 4;
            float4 v = make_float4(0.f, 0.f, 0.f, 0.f);
            if (gr < N_NODES)
                v = *(const float4*)(A + (size_t)gr * 128 + kc * 64 + kl);
            At[(kl + 0) * 128 + r_ld] = v.x;
            At[(kl + 1) * 128 + r_ld] = v.y;
            At[(kl + 2) * 128 + r_ld] = v.z;
            At[(kl + 3) * 128 + r_ld] = v.w;
        }
#pragma unroll
        for (int i = 0; i < 8; ++i) {
            *(float4*)(Wl + wk_ld * 128 + wc_ld + 4 * i) =
                *(const float4*)(W + (size_t)(kc * 64 + wk_ld) * 128 + wc_ld + 4 * i);
        }
        __syncthreads();
#pragma unroll 2
        for (int kk = 0; kk < 64; ++kk) {
            float4 a0 = *(float4*)(At + kk * 128 + ty * 8);
            float4 a1 = *(float4*)(At + kk * 128 + ty * 8 + 4);
            float4 w0 = *(float4*)(Wl + kk * 128 + tx * 8);
            float4 w1 = *(float4*)(Wl + kk * 128 + tx * 8 + 4);
            float av[8] = {a0.x, a0.y, a0.z, a0.w, a1.x, a1.y, a1.z, a1.w};
            float wv[8] = {w0.x, w0.y, w0.z, w0.w, w1.x, w1.y, w1.z, w1.w};
#pragma unroll
            for (int i = 0; i < 8; ++i)
#pragma unroll
                for (int j = 0; j < 8; ++j) acc[i][j] += av[i] * wv[j];
        }
        __syncthreads();
    }
#pragma unroll
    for (int i = 0; i < 8; ++i) {
        int gr = row0 + ty * 8 + i;
        if (gr < N_NODES) {
            float4 o0 = make_float4(acc[i][0], acc[i][1], acc[i][2], acc[i][3]);
            float4 o1 = make_float4(acc[i][4], acc[i][5], acc[i][6], acc[i][7]);
            *(float4*)(C + (size_t)gr * 128 + tx * 8)     = o0;
            *(float4*)(C + (size_t)gr * 128 + tx * 8 + 4) = o1;
        }
    }
}

__global__ __launch_bounds__(256, 2) void gemm64_dual(const float* __restrict__ A,
                                                      const float* __restrict__ W1,
                                                      const float* __restrict__ b1,
                                                      const float* __restrict__ W2,
                                                      const float* __restrict__ b2,
                                                      const float* __restrict__ avec,
                                                      float* __restrict__ C1,
                                                      float* __restrict__ C2,
                                                      float* __restrict__ ta) {
    __shared__ float At[64 * 128];   // [k][r]  32KB
    __shared__ float W1l[64 * 64];   // 16KB
    __shared__ float W2l[64 * 64];   // 16KB
    int tid  = threadIdx.x;
    int row0 = blockIdx.x * 128;
    int tx = tid & 7;                // c0 = tx*8
    int ty = tid >> 3;               // r0 = ty*4 (ty 0..31)
    float acc1[4][8], acc2[4][8];
#pragma unroll
    for (int i = 0; i < 4; ++i)
#pragma unroll
        for (int j = 0; j < 8; ++j) { acc1[i][j] = 0.f; acc2[i][j] = 0.f; }

    {
        int r_ld  = tid >> 1;
        int kb_ld = (tid & 1) * 32;
        int gr = row0 + r_ld;
#pragma unroll
        for (int i = 0; i < 8; ++i) {
            int kl = kb_ld + i * 4;
            float4 v = make_float4(0.f, 0.f, 0.f, 0.f);
            if (gr < N_NODES) v = *(const float4*)(A + (size_t)gr * 64 + kl);
            At[(kl + 0) * 128 + r_ld] = v.x;
            At[(kl + 1) * 128 + r_ld] = v.y;
            At[(kl + 2) * 128 + r_ld] = v.z;
            At[(kl + 3) * 128 + r_ld] = v.w;
        }
        int wk = tid >> 2;
        int wc = (tid & 3) * 16;
#pragma unroll
        for (int i = 0; i < 4; ++i) {
            *(float4*)(W1l + wk * 64 + wc + 4 * i) =
                *(const float4*)(W1 + (size_t)wk * 64 + wc + 4 * i);
            *(float4*)(W2l + wk * 64 + wc + 4 * i) =
                *(const float4*)(W2 + (size_t)wk * 64 + wc + 4 * i);
        }
    }
    __syncthreads();
#pragma unroll 2
    for (int k = 0; k < 64; ++k) {
        float4 a0 = *(float4*)(At + k * 128 + ty * 4);
        float4 u0 = *(float4*)(W1l + k * 64 + tx * 8);
        float4 u1 = *(float4*)(W1l + k * 64 + tx * 8 + 4);
        float4 v0 = *(float4*)(W2l + k * 64 + tx * 8);
        float4 v1 = *(float4*)(W2l + k * 64 + tx * 8 + 4);
        float av[4] = {a0.x, a0.y, a0.z, a0.w};
        float w1v[8] = {u0.x, u0.y, u0.z, u0.w, u1.x, u1.y, u1.z, u1.w};
        float w2v[8] = {v0.x, v0.y, v0.z, v0.w, v1.x, v1.y, v1.z, v1.w};
#pragma unroll
        for (int i = 0; i < 4; ++i)
#pragma unroll
            for (int j = 0; j < 8; ++j) {
                acc1[i][j] += av[i] * w1v[j];
                acc2[i][j] += av[i] * w2v[j];
            }
    }
    float b1j[8], b2j[8], aj[8];
#pragma unroll
    for (int j = 0; j < 8; ++j) {
        b1j[j] = b1[tx * 8 + j];
        b2j[j] = b2[tx * 8 + j];
        aj[j]  = avec[tx * 8 + j];
    }
#pragma unroll
    for (int i = 0; i < 4; ++i) {
        int gr = row0 + ty * 4 + i;
        float t2[8];
        float pa = 0.f;
#pragma unroll
        for (int j = 0; j < 8; ++j) {
            t2[j] = acc2[i][j] + b2j[j];
            pa += t2[j] * aj[j];
        }
        pa += __shfl_xor(pa, 1);
        pa += __shfl_xor(pa, 2);
        pa += __shfl_xor(pa, 4);
        if (gr < N_NODES) {
            float4 o0 = make_float4(acc1[i][0] + b1j[0], acc1[i][1] + b1j[1],
                                    acc1[i][2] + b1j[2], acc1[i][3] + b1j[3]);
            float4 o1 = make_float4(acc1[i][4] + b1j[4], acc1[i][5] + b1j[5],
                                    acc1[i][6] + b1j[6], acc1[i][7] + b1j[7]);
            *(float4*)(C1 + (size_t)gr * 64 + tx * 8)     = o0;
            *(float4*)(C1 + (size_t)gr * 64 + tx * 8 + 4) = o1;
            float4 p0 = make_float4(t2[0], t2[1], t2[2], t2[3]);
            float4 p1 = make_float4(t2[4], t2[5], t2[6], t2[7]);
            *(float4*)(C2 + (size_t)gr * 64 + tx * 8)     = p0;
            *(float4*)(C2 + (size_t)gr * 64 + tx * 8 + 4) = p1;
            if (tx == 0) ta[gr] = pa;
        }
    }
}

// ---------------- edge aggregation (one wave per dst) ----------------

// Batched metadata with WAVE-UNIFORM inner loop: all __shfl calls execute
// with the full wave active (loop bound nb is wave-uniform); out-of-range
// edge slots clamp the shfl source to a valid lane and contribute 0.
// lane = {sub: bit5, fl: bits0-4}; 2 row-gathers in flight per lane.
__global__ __launch_bounds__(256) void agg128(const float* __restrict__ h2,
                                              const int* __restrict__ ptrb,
                                              const int2* __restrict__ epack,
                                              const float* __restrict__ bias,
                                              float* __restrict__ out,
                                              int apply_gelu) {
    int dst  = (blockIdx.x * 256 + threadIdx.x) >> 6;
    int lane = threadIdx.x & 63;
    if (dst >= N_NODES) return;
    int sub = lane >> 5;
    int fl  = lane & 31;
    int p0 = ptrb[dst], p1 = ptrb[dst + 1];
    float4 acc0 = make_float4(0.f, 0.f, 0.f, 0.f);
    float4 acc1 = make_float4(0.f, 0.f, 0.f, 0.f);
    for (int p = p0; p < p1; p += 64) {
        int nb = min(64, p1 - p);            // wave-uniform
        int2 ed = (lane < nb) ? epack[p + lane] : make_int2(0, 0);
        int   srcs = ed.x;
        float nrm  = __int_as_float(ed.y);
        for (int eb = 0; eb < nb; eb += 4) { // uniform trip count
            int e0 = eb + sub;               // sub in {0,1}
            int e1 = e0 + 2;
            int c0 = min(e0, nb - 1);
            int c1 = min(e1, nb - 1);
            int   s0  = __shfl(srcs, c0);
            int   s1  = __shfl(srcs, c1);
            float n0r = __shfl(nrm, c0);
            float n1r = __shfl(nrm, c1);
            float n0 = (e0 < nb) ? n0r : 0.f;
            float n1 = (e1 < nb) ? n1r : 0.f;
            float4 v0 = *(const float4*)(h2 + (size_t)s0 * 128 + fl * 4);
            float4 v1 = *(const float4*)(h2 + (size_t)s1 * 128 + fl * 4);
            acc0.x += n0 * v0.x; acc0.y += n0 * v0.y;
            acc0.z += n0 * v0.z; acc0.w += n0 * v0.w;
            acc1.x += n1 * v1.x; acc1.y += n1 * v1.y;
            acc1.z += n1 * v1.z; acc1.w += n1 * v1.w;
        }
    }
    acc0.x += acc1.x; acc0.y += acc1.y; acc0.z += acc1.z; acc0.w += acc1.w;
    acc0.x += __shfl_xor(acc0.x, 32);
    acc0.y += __shfl_xor(acc0.y, 32);
    acc0.z += __shfl_xor(acc0.z, 32);
    acc0.w += __shfl_xor(acc0.w, 32);
    if (sub == 0) {
        float4 b4 = *(const float4*)(bias + fl * 4);
        float v0 = acc0.x + b4.x, v1 = acc0.y + b4.y;
        float v2 = acc0.z + b4.z, v3 = acc0.w + b4.w;
        if (apply_gelu) {
            v0 = gelu_f(v0); v1 = gelu_f(v1); v2 = gelu_f(v2); v3 = gelu_f(v3);
        }
        *(float4*)(out + (size_t)dst * 128 + fl * 4) = make_float4(v0, v1, v2, v3);
    }
}

// Single-pass edge softmax (max-shift redundant: |alpha| small), batched
// metadata + wave-wide exp, wave-uniform inner loop (see agg128 note).
// lane = {sub: bits4-5, fl: bits0-3}; 2 row-gathers in flight per lane.
__global__ __launch_bounds__(256) void gna_agg(const float* __restrict__ t,
                                               const float* __restrict__ ta,
                                               const int* __restrict__ ptrb,
                                               const int2* __restrict__ epack,
                                               const float* __restrict__ base,
                                               float* __restrict__ gout) {
    int dst  = (blockIdx.x * 256 + threadIdx.x) >> 6;
    int lane = threadIdx.x & 63;
    if (dst >= N_NODES) return;
    int p0 = ptrb[dst], p1 = ptrb[dst + 1];
    float tac = ta[dst];
    int sub = lane >> 4;
    int fl  = lane & 15;
    float se = 0.f;
    float4 m0 = make_float4(0.f, 0.f, 0.f, 0.f);
    float4 m1 = make_float4(0.f, 0.f, 0.f, 0.f);
    for (int p = p0; p < p1; p += 64) {
        int nb = min(64, p1 - p);            // wave-uniform
        int2 ed = (lane < nb) ? epack[p + lane] : make_int2(0, 0);
        int srcs = ed.x;
        float tav = (lane < nb) ? ta[srcs] : tac;
        float ev  = expf(tac - tav);         // wave-wide: 64 exps in one go
        if (lane < nb) se += ev;
        for (int eb = 0; eb < nb; eb += 8) { // uniform trip count
            int e0 = eb + sub;               // sub in {0,1,2,3}
            int e1 = e0 + 4;
            int c0 = min(e0, nb - 1);
            int c1 = min(e1, nb - 1);
            int   s0  = __shfl(srcs, c0);
            int   s1  = __shfl(srcs, c1);
            float w0r = __shfl(ev, c0);
            float w1r = __shfl(ev, c1);
            float w0 = (e0 < nb) ? w0r : 0.f;
            float w1 = (e1 < nb) ? w1r : 0.f;
            float4 v0 = *(const float4*)(t + (size_t)s0 * 64 + fl * 4);
            float4 v1 = *(const float4*)(t + (size_t)s1 * 64 + fl * 4);
            m0.x += w0 * v0.x; m0.y += w0 * v0.y;
            m0.z += w0 * v0.z; m0.w += w0 * v0.w;
            m1.x += w1 * v1.x; m1.y += w1 * v1.y;
            m1.z += w1 * v1.z; m1.w += w1 * v1.w;
        }
    }
#pragma unroll
    for (int off = 1; off < 64; off <<= 1) se += __shfl_xor(se, off);
    m0.x += m1.x; m0.y += m1.y; m0.z += m1.z; m0.w += m1.w;
#pragma unroll
    for (int off = 16; off <= 32; off <<= 1) {
        m0.x += __shfl_xor(m0.x, off);
        m0.y += __shfl_xor(m0.y, off);
        m0.z += __shfl_xor(m0.z, off);
        m0.w += __shfl_xor(m0.w, off);
    }
    if (lane < 16) {
        float winv = 1.0f / (se + 1e-16f);
        float4 bs = *(const float4*)(base + (size_t)dst * 64 + fl * 4);
        float v0 = bs.x + m0.x * winv;
        float v1 = bs.y + m0.y * winv;
        float v2 = bs.z + m0.z * winv;
        float v3 = bs.w + m0.w * winv;
        *(float4*)(gout + (size_t)dst * 64 + fl * 4) =
            make_float4(gelu_f(v0), gelu_f(v1), gelu_f(v2), gelu_f(v3));
    }
}

// ---------------- launch ----------------

extern "C" void kernel_launch(void* const* d_in, const int* in_sizes, int n_in,
                              void* d_out, int out_size, void* d_ws, size_t ws_size,
                              hipStream_t stream) {
    const float* x     = (const float*)d_in[0];
    const float* s     = (const float*)d_in[1];
    const int*   ei    = (const int*)d_in[2];
    const float* gcn_W = (const float*)d_in[3];
    const float* gcn_b = (const float*)d_in[4];
    const float* w1W   = (const float*)d_in[5];
    const float* w1b   = (const float*)d_in[6];
    const float* w2W   = (const float*)d_in[7];
    const float* w2b   = (const float*)d_in[8];
    const float* ga    = (const float*)d_in[9];

    float* h_out = (float*)d_out;                               // N x 128
    float* g_out = (float*)d_out + (size_t)N_NODES * 128;       // N x 64

    size_t off = 0;
    char* wsb = (char*)d_ws;
    auto take = [&](size_t bytes) {
        void* p = wsb + off;
        off = (off + bytes + 255) & ~(size_t)255;
        return p;
    };
    int*   cnt     = (int*)take((size_t)N_NODES * 4);
    int*   ptrb    = (int*)take((size_t)(N_NODES + 1) * 4);
    int*   aux     = (int*)take((size_t)ET * 4);
    float* dinv    = (float*)take((size_t)N_NODES * 4);
    int2*  epack   = (int2*)take((size_t)ET * 8);
    float* h2      = (float*)take((size_t)N_NODES * 128 * 4);
    float* tbuf    = (float*)take((size_t)N_NODES * 64 * 4);
    float* basebuf = (float*)take((size_t)N_NODES * 64 * 4);
    float* tabuf   = (float*)take((size_t)N_NODES * 4);
    int*   bsum    = (int*)take((size_t)NB_SCAN * 4);
    (void)ws_size; (void)in_sizes; (void)n_in; (void)out_size;

    const int* erow = ei;
    const int* ecol = ei + E_EDGES;

    hipMemsetAsync(cnt, 0, (size_t)N_NODES * 4, stream);

    int ge = (ET + 255) / 256;
    count_pos<<<ge, 256, 0, stream>>>(ecol, cnt, aux);
    scan_part1<<<NB_SCAN, 256, 0, stream>>>(cnt, bsum);
    scan_part2<<<1, 256, 0, stream>>>(bsum);
    scan_part3<<<NB_SCAN, 256, 0, stream>>>(cnt, bsum, ptrb, dinv);
    bucket<<<ge, 256, 0, stream>>>(erow, ecol, aux, ptrb, dinv, epack);

    const int gemm_blocks = (N_NODES + 127) / 128;       // 391
    const int wave_blocks = (N_NODES * 64 + 255) / 256;  // 12500

    // ---- GCN ----
    const float* hin = x;
    for (int l = 0; l < L_LAYERS; ++l) {
        gemm128<<<gemm_blocks, 256, 0, stream>>>(hin, gcn_W + (size_t)l * 128 * 128, h2);
        agg128<<<wave_blocks, 256, 0, stream>>>(h2, ptrb, epack,
                                                gcn_b + (size_t)l * 128, h_out,
                                                (l < L_LAYERS - 1) ? 1 : 0);
        hin = h_out;
    }

    // ---- GNA ----
    const float* gin = s;
    for (int l = 0; l < L_LAYERS; ++l) {
        gemm64_dual<<<gemm_blocks, 256, 0, stream>>>(
            gin,
            w1W + (size_t)l * 64 * 64, w1b + (size_t)l * 64,
            w2W + (size_t)l * 64 * 64, w2b + (size_t)l * 64,
            ga + (size_t)l * 64,
            basebuf, tbuf, tabuf);
        gna_agg<<<wave_blocks, 256, 0, stream>>>(tbuf, tabuf, ptrb, epack, basebuf, g_out);
        gin = g_out;
    }
}

// Round 6
// 738.424 us; speedup vs baseline: 1.8077x; 1.0035x over previous
//
#include <hip/hip_runtime.h>
#include <math.h>

#define N_NODES 50000
#define E_EDGES 800000
#define ET (E_EDGES + N_NODES)   // edges + self loops
#define L_LAYERS 4
#define NB_SCAN ((N_NODES + 255) / 256)   // 196

__device__ __forceinline__ float gelu_f(float x) {
    return 0.5f * x * (1.0f + erff(x * 0.70710678118654752f));
}

// ---------------- graph preprocessing ----------------

// counts degree AND records each edge's position within its dst bucket
// (the atomicAdd return value) so the bucket pass needs no atomics.
__global__ __launch_bounds__(256) void count_pos(const int* __restrict__ ecol,
                                                 int* __restrict__ cnt,
                                                 int* __restrict__ aux) {
    int e = blockIdx.x * 256 + threadIdx.x;
    if (e >= ET) return;
    int c = (e < E_EDGES) ? ecol[e] : (e - E_EDGES);
    aux[e] = atomicAdd(&cnt[c], 1);
}

__global__ __launch_bounds__(256) void scan_part1(const int* __restrict__ cnt,
                                                  int* __restrict__ bsum) {
    __shared__ int red[256];
    int t = threadIdx.x;
    int i = blockIdx.x * 256 + t;
    red[t] = (i < N_NODES) ? cnt[i] : 0;
    __syncthreads();
#pragma unroll
    for (int off = 128; off; off >>= 1) {
        if (t < off) red[t] += red[t + off];
        __syncthreads();
    }
    if (t == 0) bsum[blockIdx.x] = red[0];
}

__global__ __launch_bounds__(256) void scan_part2(int* __restrict__ bsum) {
    __shared__ int sh[256];
    int t = threadIdx.x;
    int v = (t < NB_SCAN) ? bsum[t] : 0;
    sh[t] = v;
    __syncthreads();
    for (int off = 1; off < 256; off <<= 1) {
        int u = (t >= off) ? sh[t - off] : 0;
        __syncthreads();
        sh[t] += u;
        __syncthreads();
    }
    if (t < NB_SCAN) bsum[t] = sh[t] - v;   // exclusive
}

__global__ __launch_bounds__(256) void scan_part3(const int* __restrict__ cnt,
                                                  const int* __restrict__ bsum,
                                                  int* __restrict__ ptrb,
                                                  float* __restrict__ dinv) {
    __shared__ int sh[256];
    int t = threadIdx.x;
    int i = blockIdx.x * 256 + t;
    int v = (i < N_NODES) ? cnt[i] : 0;
    sh[t] = v;
    __syncthreads();
    for (int off = 1; off < 256; off <<= 1) {
        int u = (t >= off) ? sh[t - off] : 0;
        __syncthreads();
        sh[t] += u;
        __syncthreads();
    }
    int excl = sh[t] - v + bsum[blockIdx.x];
    if (i < N_NODES) {
        ptrb[i] = excl;
        dinv[i] = rsqrtf((float)v);   // deg >= 1 (self loop)
    }
    if (i == N_NODES - 1) ptrb[N_NODES] = excl + v;
}

__global__ __launch_bounds__(256) void bucket(const int* __restrict__ erow,
                                              const int* __restrict__ ecol,
                                              const int* __restrict__ aux,
                                              const int* __restrict__ ptrb,
                                              const float* __restrict__ dinv,
                                              int2* __restrict__ epack) {
    int e = blockIdx.x * 256 + threadIdx.x;
    if (e >= ET) return;
    int r, c;
    if (e < E_EDGES) { r = erow[e]; c = ecol[e]; }
    else             { r = e - E_EDGES; c = r; }
    int pos = ptrb[c] + aux[e];
    epack[pos] = make_int2(r, __float_as_int(dinv[r] * dinv[c]));
}

// ---------------- GEMMs (f32, vector ALU; no fp32 MFMA on CDNA4) ----------------

__global__ __launch_bounds__(256, 2) void gemm128(const float* __restrict__ A,
                                                  const float* __restrict__ W,
                                                  float* __restrict__ C) {
    __shared__ float At[64 * 128];   // [kk][r]
    __shared__ float Wl[64 * 128];   // [kk][c]
    int tid  = threadIdx.x;
    int row0 = blockIdx.x * 128;
    int tx = tid & 15;               // c0 = tx*8
    int ty = tid >> 4;               // r0 = ty*8
    float acc[8][8];
#pragma unroll
    for (int i = 0; i < 8; ++i)
#pragma unroll
        for (int j = 0; j < 8; ++j) acc[i][j] = 0.f;

    const int r_ld  = tid >> 1;
    const int kb_ld = (tid & 1) * 32;
    const int wk_ld = tid >> 2;
    const int wc_ld = (tid & 3) * 32;

    for (int kc = 0; kc < 2; ++kc) {
        int gr = row0 + r_ld;
#pragma unroll
        for (int i = 0; i < 8; ++i) {
            int kl = kb_ld + i * 4;
            float4 v = make_float4(0.f, 0.f, 0.f, 0.f);
            if (gr < N_NODES)
                v = *(const float4*)(A + (size_t)gr * 128 + kc * 64 + kl);
            At[(kl + 0) * 128 + r_ld] = v.x;
            At[(kl + 1) * 128 + r_ld] = v.y;
            At[(kl + 2) * 128 + r_ld] = v.z;
            At[(kl + 3) * 128 + r_ld] = v.w;
        }
#pragma unroll
        for (int i = 0; i < 8; ++i) {
            *(float4*)(Wl + wk_ld * 128 + wc_ld + 4 * i) =
                *(const float4*)(W + (size_t)(kc * 64 + wk_ld) * 128 + wc_ld + 4 * i);
        }
        __syncthreads();
#pragma unroll 2
        for (int kk = 0; kk < 64; ++kk) {
            float4 a0 = *(float4*)(At + kk * 128 + ty * 8);
            float4 a1 = *(float4*)(At + kk * 128 + ty * 8 + 4);
            float4 w0 = *(float4*)(Wl + kk * 128 + tx * 8);
            float4 w1 = *(float4*)(Wl + kk * 128 + tx * 8 + 4);
            float av[8] = {a0.x, a0.y, a0.z, a0.w, a1.x, a1.y, a1.z, a1.w};
            float wv[8] = {w0.x, w0.y, w0.z, w0.w, w1.x, w1.y, w1.z, w1.w};
#pragma unroll
            for (int i = 0; i < 8; ++i)
#pragma unroll
                for (int j = 0; j < 8; ++j) acc[i][j] += av[i] * wv[j];
        }
        __syncthreads();
    }
#pragma unroll
    for (int i = 0; i < 8; ++i) {
        int gr = row0 + ty * 8 + i;
        if (gr < N_NODES) {
            float4 o0 = make_float4(acc[i][0], acc[i][1], acc[i][2], acc[i][3]);
            float4 o1 = make_float4(acc[i][4], acc[i][5], acc[i][6], acc[i][7]);
            *(float4*)(C + (size_t)gr * 128 + tx * 8)     = o0;
            *(float4*)(C + (size_t)gr * 128 + tx * 8 + 4) = o1;
        }
    }
}

__global__ __launch_bounds__(256, 2) void gemm64_dual(const float* __restrict__ A,
                                                      const float* __restrict__ W1,
                                                      const float* __restrict__ b1,
                                                      const float* __restrict__ W2,
                                                      const float* __restrict__ b2,
                                                      const float* __restrict__ avec,
                                                      float* __restrict__ C1,
                                                      float* __restrict__ C2,
                                                      float* __restrict__ ta) {
    __shared__ float At[64 * 128];   // [k][r]  32KB
    __shared__ float W1l[64 * 64];   // 16KB
    __shared__ float W2l[64 * 64];   // 16KB
    int tid  = threadIdx.x;
    int row0 = blockIdx.x * 128;
    int tx = tid & 7;                // c0 = tx*8
    int ty = tid >> 3;               // r0 = ty*4 (ty 0..31)
    float acc1[4][8], acc2[4][8];
#pragma unroll
    for (int i = 0; i < 4; ++i)
#pragma unroll
        for (int j = 0; j < 8; ++j) { acc1[i][j] = 0.f; acc2[i][j] = 0.f; }

    {
        int r_ld  = tid >> 1;
        int kb_ld = (tid & 1) * 32;
        int gr = row0 + r_ld;
#pragma unroll
        for (int i = 0; i < 8; ++i) {
            int kl = kb_ld + i * 4;
            float4 v = make_float4(0.f, 0.f, 0.f, 0.f);
            if (gr < N_NODES) v = *(const float4*)(A + (size_t)gr * 64 + kl);
            At[(kl + 0) * 128 + r_ld] = v.x;
            At[(kl + 1) * 128 + r_ld] = v.y;
            At[(kl + 2) * 128 + r_ld] = v.z;
            At[(kl + 3) * 128 + r_ld] = v.w;
        }
        int wk = tid >> 2;
        int wc = (tid & 3) * 16;
#pragma unroll
        for (int i = 0; i < 4; ++i) {
            *(float4*)(W1l + wk * 64 + wc + 4 * i) =
                *(const float4*)(W1 + (size_t)wk * 64 + wc + 4 * i);
            *(float4*)(W2l + wk * 64 + wc + 4 * i) =
                *(const float4*)(W2 + (size_t)wk * 64 + wc + 4 * i);
        }
    }
    __syncthreads();
#pragma unroll 2
    for (int k = 0; k < 64; ++k) {
        float4 a0 = *(float4*)(At + k * 128 + ty * 4);
        float4 u0 = *(float4*)(W1l + k * 64 + tx * 8);
        float4 u1 = *(float4*)(W1l + k * 64 + tx * 8 + 4);
        float4 v0 = *(float4*)(W2l + k * 64 + tx * 8);
        float4 v1 = *(float4*)(W2l + k * 64 + tx * 8 + 4);
        float av[4] = {a0.x, a0.y, a0.z, a0.w};
        float w1v[8] = {u0.x, u0.y, u0.z, u0.w, u1.x, u1.y, u1.z, u1.w};
        float w2v[8] = {v0.x, v0.y, v0.z, v0.w, v1.x, v1.y, v1.z, v1.w};
#pragma unroll
        for (int i = 0; i < 4; ++i)
#pragma unroll
            for (int j = 0; j < 8; ++j) {
                acc1[i][j] += av[i] * w1v[j];
                acc2[i][j] += av[i] * w2v[j];
            }
    }
    float b1j[8], b2j[8], aj[8];
#pragma unroll
    for (int j = 0; j < 8; ++j) {
        b1j[j] = b1[tx * 8 + j];
        b2j[j] = b2[tx * 8 + j];
        aj[j]  = avec[tx * 8 + j];
    }
#pragma unroll
    for (int i = 0; i < 4; ++i) {
        int gr = row0 + ty * 4 + i;
        float t2[8];
        float pa = 0.f;
#pragma unroll
        for (int j = 0; j < 8; ++j) {
            t2[j] = acc2[i][j] + b2j[j];
            pa += t2[j] * aj[j];
        }
        pa += __shfl_xor(pa, 1);
        pa += __shfl_xor(pa, 2);
        pa += __shfl_xor(pa, 4);
        if (gr < N_NODES) {
            float4 o0 = make_float4(acc1[i][0] + b1j[0], acc1[i][1] + b1j[1],
                                    acc1[i][2] + b1j[2], acc1[i][3] + b1j[3]);
            float4 o1 = make_float4(acc1[i][4] + b1j[4], acc1[i][5] + b1j[5],
                                    acc1[i][6] + b1j[6], acc1[i][7] + b1j[7]);
            *(float4*)(C1 + (size_t)gr * 64 + tx * 8)     = o0;
            *(float4*)(C1 + (size_t)gr * 64 + tx * 8 + 4) = o1;
            float4 p0 = make_float4(t2[0], t2[1], t2[2], t2[3]);
            float4 p1 = make_float4(t2[4], t2[5], t2[6], t2[7]);
            *(float4*)(C2 + (size_t)gr * 64 + tx * 8)     = p0;
            *(float4*)(C2 + (size_t)gr * 64 + tx * 8 + 4) = p1;
            if (tx == 0) ta[gr] = pa;
        }
    }
}

// ---------------- edge aggregation (one wave per dst) ----------------

// Batched metadata, wave-uniform control flow, 4 independent row-gathers in
// flight per lane (shfl-broadcast x4, then 4 loads, then 4 FMA blocks).
// lane = {sub: bit5, fl: bits0-4}; edges e = eb + sub + 2k, k=0..3.
__global__ __launch_bounds__(256) void agg128(const float* __restrict__ h2,
                                              const int* __restrict__ ptrb,
                                              const int2* __restrict__ epack,
                                              const float* __restrict__ bias,
                                              float* __restrict__ out,
                                              int apply_gelu) {
    int dst  = (blockIdx.x * 256 + threadIdx.x) >> 6;
    int lane = threadIdx.x & 63;
    if (dst >= N_NODES) return;
    int sub = lane >> 5;
    int fl  = lane & 31;
    int p0 = ptrb[dst], p1 = ptrb[dst + 1];
    float4 acc[4];
#pragma unroll
    for (int k = 0; k < 4; ++k) acc[k] = make_float4(0.f, 0.f, 0.f, 0.f);
    for (int p = p0; p < p1; p += 64) {
        int nb = min(64, p1 - p);            // wave-uniform
        int2 ed = (lane < nb) ? epack[p + lane] : make_int2(0, 0);
        int   srcs = ed.x;
        float nrm  = __int_as_float(ed.y);
        for (int eb = 0; eb < nb; eb += 8) { // uniform trip count
            int   sv[4];
            float nv[4];
#pragma unroll
            for (int k = 0; k < 4; ++k) {
                int e = eb + sub + 2 * k;    // sub in {0,1}
                int c = min(e, nb - 1);
                sv[k] = __shfl(srcs, c);
                float nr = __shfl(nrm, c);
                nv[k] = (e < nb) ? nr : 0.f;
            }
            float4 v[4];
#pragma unroll
            for (int k = 0; k < 4; ++k)
                v[k] = *(const float4*)(h2 + (size_t)sv[k] * 128 + fl * 4);
#pragma unroll
            for (int k = 0; k < 4; ++k) {
                acc[k].x += nv[k] * v[k].x; acc[k].y += nv[k] * v[k].y;
                acc[k].z += nv[k] * v[k].z; acc[k].w += nv[k] * v[k].w;
            }
        }
    }
    float4 a = acc[0];
    a.x += acc[1].x + acc[2].x + acc[3].x;
    a.y += acc[1].y + acc[2].y + acc[3].y;
    a.z += acc[1].z + acc[2].z + acc[3].z;
    a.w += acc[1].w + acc[2].w + acc[3].w;
    a.x += __shfl_xor(a.x, 32);
    a.y += __shfl_xor(a.y, 32);
    a.z += __shfl_xor(a.z, 32);
    a.w += __shfl_xor(a.w, 32);
    if (sub == 0) {
        float4 b4 = *(const float4*)(bias + fl * 4);
        float v0 = a.x + b4.x, v1 = a.y + b4.y;
        float v2 = a.z + b4.z, v3 = a.w + b4.w;
        if (apply_gelu) {
            v0 = gelu_f(v0); v1 = gelu_f(v1); v2 = gelu_f(v2); v3 = gelu_f(v3);
        }
        *(float4*)(out + (size_t)dst * 128 + fl * 4) = make_float4(v0, v1, v2, v3);
    }
}

// Single-pass edge softmax (max-shift redundant: |alpha| small), batched
// metadata + wave-wide exp, 4 gathers in flight per lane.
// lane = {sub: bits4-5, fl: bits0-3}; edges e = eb + sub + 4k, k=0..3.
__global__ __launch_bounds__(256) void gna_agg(const float* __restrict__ t,
                                               const float* __restrict__ ta,
                                               const int* __restrict__ ptrb,
                                               const int2* __restrict__ epack,
                                               const float* __restrict__ base,
                                               float* __restrict__ gout) {
    int dst  = (blockIdx.x * 256 + threadIdx.x) >> 6;
    int lane = threadIdx.x & 63;
    if (dst >= N_NODES) return;
    int p0 = ptrb[dst], p1 = ptrb[dst + 1];
    float tac = ta[dst];
    int sub = lane >> 4;
    int fl  = lane & 15;
    float se = 0.f;
    float4 m[4];
#pragma unroll
    for (int k = 0; k < 4; ++k) m[k] = make_float4(0.f, 0.f, 0.f, 0.f);
    for (int p = p0; p < p1; p += 64) {
        int nb = min(64, p1 - p);            // wave-uniform
        int2 ed = (lane < nb) ? epack[p + lane] : make_int2(0, 0);
        int srcs = ed.x;
        float tav = (lane < nb) ? ta[srcs] : tac;
        float ev  = expf(tac - tav);         // wave-wide: 64 exps in one go
        if (lane < nb) se += ev;
        for (int eb = 0; eb < nb; eb += 16) { // uniform trip count
            int   sv[4];
            float wv[4];
#pragma unroll
            for (int k = 0; k < 4; ++k) {
                int e = eb + sub + 4 * k;    // sub in {0,1,2,3}
                int c = min(e, nb - 1);
                sv[k] = __shfl(srcs, c);
                float wr = __shfl(ev, c);
                wv[k] = (e < nb) ? wr : 0.f;
            }
            float4 v[4];
#pragma unroll
            for (int k = 0; k < 4; ++k)
                v[k] = *(const float4*)(t + (size_t)sv[k] * 64 + fl * 4);
#pragma unroll
            for (int k = 0; k < 4; ++k) {
                m[k].x += wv[k] * v[k].x; m[k].y += wv[k] * v[k].y;
                m[k].z += wv[k] * v[k].z; m[k].w += wv[k] * v[k].w;
            }
        }
    }
#pragma unroll
    for (int off = 1; off < 64; off <<= 1) se += __shfl_xor(se, off);
    float4 mm = m[0];
    mm.x += m[1].x + m[2].x + m[3].x;
    mm.y += m[1].y + m[2].y + m[3].y;
    mm.z += m[1].z + m[2].z + m[3].z;
    mm.w += m[1].w + m[2].w + m[3].w;
#pragma unroll
    for (int off = 16; off <= 32; off <<= 1) {
        mm.x += __shfl_xor(mm.x, off);
        mm.y += __shfl_xor(mm.y, off);
        mm.z += __shfl_xor(mm.z, off);
        mm.w += __shfl_xor(mm.w, off);
    }
    if (lane < 16) {
        float winv = 1.0f / (se + 1e-16f);
        float4 bs = *(const float4*)(base + (size_t)dst * 64 + fl * 4);
        float v0 = bs.x + mm.x * winv;
        float v1 = bs.y + mm.y * winv;
        float v2 = bs.z + mm.z * winv;
        float v3 = bs.w + mm.w * winv;
        *(float4*)(gout + (size_t)dst * 64 + fl * 4) =
            make_float4(gelu_f(v0), gelu_f(v1), gelu_f(v2), gelu_f(v3));
    }
}

// ---------------- launch ----------------

extern "C" void kernel_launch(void* const* d_in, const int* in_sizes, int n_in,
                              void* d_out, int out_size, void* d_ws, size_t ws_size,
                              hipStream_t stream) {
    const float* x     = (const float*)d_in[0];
    const float* s     = (const float*)d_in[1];
    const int*   ei    = (const int*)d_in[2];
    const float* gcn_W = (const float*)d_in[3];
    const float* gcn_b = (const float*)d_in[4];
    const float* w1W   = (const float*)d_in[5];
    const float* w1b   = (const float*)d_in[6];
    const float* w2W   = (const float*)d_in[7];
    const float* w2b   = (const float*)d_in[8];
    const float* ga    = (const float*)d_in[9];

    float* h_out = (float*)d_out;                               // N x 128
    float* g_out = (float*)d_out + (size_t)N_NODES * 128;       // N x 64

    size_t off = 0;
    char* wsb = (char*)d_ws;
    auto take = [&](size_t bytes) {
        void* p = wsb + off;
        off = (off + bytes + 255) & ~(size_t)255;
        return p;
    };
    int*   cnt     = (int*)take((size_t)N_NODES * 4);
    int*   ptrb    = (int*)take((size_t)(N_NODES + 1) * 4);
    int*   aux     = (int*)take((size_t)ET * 4);
    float* dinv    = (float*)take((size_t)N_NODES * 4);
    int2*  epack   = (int2*)take((size_t)ET * 8);
    float* h2      = (float*)take((size_t)N_NODES * 128 * 4);
    float* tbuf    = (float*)take((size_t)N_NODES * 64 * 4);
    float* basebuf = (float*)take((size_t)N_NODES * 64 * 4);
    float* tabuf   = (float*)take((size_t)N_NODES * 4);
    int*   bsum    = (int*)take((size_t)NB_SCAN * 4);
    (void)ws_size; (void)in_sizes; (void)n_in; (void)out_size;

    const int* erow = ei;
    const int* ecol = ei + E_EDGES;

    hipMemsetAsync(cnt, 0, (size_t)N_NODES * 4, stream);

    int ge = (ET + 255) / 256;
    count_pos<<<ge, 256, 0, stream>>>(ecol, cnt, aux);
    scan_part1<<<NB_SCAN, 256, 0, stream>>>(cnt, bsum);
    scan_part2<<<1, 256, 0, stream>>>(bsum);
    scan_part3<<<NB_SCAN, 256, 0, stream>>>(cnt, bsum, ptrb, dinv);
    bucket<<<ge, 256, 0, stream>>>(erow, ecol, aux, ptrb, dinv, epack);

    const int gemm_blocks = (N_NODES + 127) / 128;       // 391
    const int wave_blocks = (N_NODES * 64 + 255) / 256;  // 12500

    // ---- GCN ----
    const float* hin = x;
    for (int l = 0; l < L_LAYERS; ++l) {
        gemm128<<<gemm_blocks, 256, 0, stream>>>(hin, gcn_W + (size_t)l * 128 * 128, h2);
        agg128<<<wave_blocks, 256, 0, stream>>>(h2, ptrb, epack,
                                                gcn_b + (size_t)l * 128, h_out,
                                                (l < L_LAYERS - 1) ? 1 : 0);
        hin = h_out;
    }

    // ---- GNA ----
    const float* gin = s;
    for (int l = 0; l < L_LAYERS; ++l) {
        gemm64_dual<<<gemm_blocks, 256, 0, stream>>>(
            gin,
            w1W + (size_t)l * 64 * 64, w1b + (size_t)l * 64,
            w2W + (size_t)l * 64 * 64, w2b + (size_t)l * 64,
            ga + (size_t)l * 64,
            basebuf, tbuf, tabuf);
        gna_agg<<<wave_blocks, 256, 0, stream>>>(tbuf, tabuf, ptrb, epack, basebuf, g_out);
        gin = g_out;
    }
}